// Round 1
// baseline (5693.966 us; speedup 1.0000x reference)
//
#include <hip/hip_runtime.h>

#define HW 147456
#define WID 384
#define NB 8
#define NPC 1179648   // per-channel element count = 8*384*384
#define NSPLIT 64

static __device__ __forceinline__ float lrelu01(float v) { return v >= 0.f ? v : 0.01f * v; }
static __device__ __forceinline__ float mlrelu(float v) { return v > 0.1f ? 0.1f + 0.7f * (v - 0.1f) : v; }

// ---------------------------------------------------------------------------
// Mode pool: quantize x to 17 bins, 11x11 window mode (zero pad -> bin 0),
// first-max tie break (smallest bin). Output xm = bin * 0.0625.
// Grid: (6 xtiles of 64, 24 ytiles of 16, 24 planes), block 256.
// ---------------------------------------------------------------------------
__global__ __launch_bounds__(256) void mode_kernel(const float* __restrict__ x,
                                                   float* __restrict__ xm) {
  __shared__ unsigned char qt[26 * 76];
  __shared__ unsigned int cc[16 * 5 * 76];   // [y][word][col]
  const int plane = blockIdx.z;
  const int x0 = blockIdx.x * 64;
  const int y0 = blockIdx.y * 16;
  const float* xp = x + (size_t)plane * HW;

  for (int i = threadIdx.x; i < 26 * 76; i += 256) {
    int r = i / 76, ccol = i - r * 76;
    int gy = y0 + r - 5, gx = x0 + ccol - 5;
    unsigned char q = 0;
    if (ccol < 74 && gy >= 0 && gy < WID && gx >= 0 && gx < WID) {
      float v = xp[gy * WID + gx];
      int qi = (int)rintf(v * 15.9375f);
      qi = qi < 0 ? 0 : (qi > 16 ? 16 : qi);
      q = (unsigned char)qi;
    }
    qt[i] = q;
  }
  __syncthreads();

  for (int i = threadIdx.x; i < 16 * 74; i += 256) {
    int yy = i / 74, col = i - yy * 74;
    unsigned int w0 = 0, w1 = 0, w2 = 0, w3 = 0, w4 = 0;
#pragma unroll
    for (int dy = 0; dy < 11; ++dy) {
      int q = qt[(yy + dy) * 76 + col];
      unsigned int inc = 1u << ((q & 3) << 3);
      int wsel = q >> 2;
      w0 += (wsel == 0) ? inc : 0u;
      w1 += (wsel == 1) ? inc : 0u;
      w2 += (wsel == 2) ? inc : 0u;
      w3 += (wsel == 3) ? inc : 0u;
      w4 += (wsel == 4) ? inc : 0u;
    }
    cc[(yy * 5 + 0) * 76 + col] = w0;
    cc[(yy * 5 + 1) * 76 + col] = w1;
    cc[(yy * 5 + 2) * 76 + col] = w2;
    cc[(yy * 5 + 3) * 76 + col] = w3;
    cc[(yy * 5 + 4) * 76 + col] = w4;
  }
  __syncthreads();

  for (int i = threadIdx.x; i < 16 * 64; i += 256) {
    int yy = i / 64, xx = i - yy * 64;
    unsigned int s0 = 0, s1 = 0, s2 = 0, s3 = 0, s4 = 0;
#pragma unroll
    for (int dx = 0; dx < 11; ++dx) {
      int col = xx + dx;
      s0 += cc[(yy * 5 + 0) * 76 + col];
      s1 += cc[(yy * 5 + 1) * 76 + col];
      s2 += cc[(yy * 5 + 2) * 76 + col];
      s3 += cc[(yy * 5 + 3) * 76 + col];
      s4 += cc[(yy * 5 + 4) * 76 + col];
    }
    unsigned int words[5] = {s0, s1, s2, s3, s4};
    int best = 0;
    unsigned int bc = s0 & 0xffu;
#pragma unroll
    for (int bin = 1; bin < 17; ++bin) {
      unsigned int cnt = (words[bin >> 2] >> ((bin & 3) * 8)) & 0xffu;
      if (cnt > bc) { bc = cnt; best = bin; }
    }
    xm[(size_t)plane * HW + (size_t)(y0 + yy) * WID + (x0 + xx)] = best * 0.0625f;
  }
}

// ---------------------------------------------------------------------------
// prepare layer 1: 1x1 conv (3->32) + bias + per-channel scale/shift
// ---------------------------------------------------------------------------
__global__ __launch_bounds__(256) void prep_conv1(const float* __restrict__ xm,
                                                  const float* __restrict__ w1,
                                                  const float* __restrict__ b1,
                                                  const float* __restrict__ dw1,
                                                  const float* __restrict__ db1,
                                                  float* __restrict__ t1) {
  int idx = blockIdx.x * 256 + threadIdx.x;
  if (idx >= NB * HW) return;
  int b = idx / HW, p = idx - b * HW;
  float x0 = xm[(size_t)(b * 3 + 0) * HW + p];
  float x1 = xm[(size_t)(b * 3 + 1) * HW + p];
  float x2 = xm[(size_t)(b * 3 + 2) * HW + p];
  size_t base = (size_t)b * 32 * HW + p;
#pragma unroll 8
  for (int o = 0; o < 32; ++o) {
    float v = x0 * w1[o * 3] + x1 * w1[o * 3 + 1] + x2 * w1[o * 3 + 2] + b1[o];
    v = v * dw1[o] + db1[o];
    t1[base + (size_t)o * HW] = v;
  }
}

// ---------------------------------------------------------------------------
// prepare layer 2: bn1+lrelu applied on read, 1x1 conv (32->32) + bias + scale
// ---------------------------------------------------------------------------
__global__ __launch_bounds__(256) void prep_conv2(const float* __restrict__ t1,
                                                  const float* __restrict__ sc1,
                                                  const float* __restrict__ sh1,
                                                  const float* __restrict__ w2,
                                                  const float* __restrict__ b2,
                                                  const float* __restrict__ dw2,
                                                  const float* __restrict__ db2,
                                                  float* __restrict__ t2) {
  __shared__ float wl[1024];
  for (int i = threadIdx.x; i < 1024; i += 256) wl[i] = w2[i];
  __syncthreads();
  int idx = blockIdx.x * 256 + threadIdx.x;
  if (idx >= NB * HW) return;
  int b = idx / HW, p = idx - b * HW;
  size_t base = (size_t)b * 32 * HW + p;
  float h[32];
#pragma unroll
  for (int c = 0; c < 32; ++c) {
    float v = t1[base + (size_t)c * HW];
    v = v * sc1[c] + sh1[c];
    h[c] = lrelu01(v);
  }
  for (int o = 0; o < 32; ++o) {
    float acc = b2[o];
#pragma unroll
    for (int c = 0; c < 32; ++c) acc = fmaf(h[c], wl[o * 32 + c], acc);
    acc = acc * dw2[o] + db2[o];
    t2[base + (size_t)o * HW] = acc;
  }
}

// ---------------------------------------------------------------------------
// per-channel stats partial: sum & sumsq over (B, :, HW) slice.
// MODE 0: raw; MODE 1: maxlrelu(x*sc+sh) (ft intermediate).
// grid = C * NSPLIT blocks.
// ---------------------------------------------------------------------------
template <int MODE>
__global__ __launch_bounds__(256) void stats_partial(const float* __restrict__ x,
                                                     const float* __restrict__ sc,
                                                     const float* __restrict__ sh,
                                                     float* __restrict__ part, int C) {
  const int c = blockIdx.x / NSPLIT;
  const int s = blockIdx.x - c * NSPLIT;
  const int chunk = NPC / NSPLIT;
  float fsc = 0.f, fsh = 0.f;
  if (MODE == 1) { fsc = sc[c]; fsh = sh[c]; }
  int i = s * chunk + threadIdx.x;
  int b = i / HW, p = i - b * HW;
  const int end = (s + 1) * chunk;
  float sum = 0.f, sq = 0.f;
  for (; i < end; i += 256) {
    float v = x[((size_t)b * C + c) * HW + p];
    if (MODE == 1) { v = v * fsc + fsh; v = mlrelu(v); }
    sum += v;
    sq += v * v;
    p += 256;
    if (p >= HW) { p -= HW; ++b; }
  }
  int lane = threadIdx.x & 63, wid = threadIdx.x >> 6;
  for (int off = 32; off; off >>= 1) {
    sum += __shfl_down(sum, off);
    sq += __shfl_down(sq, off);
  }
  __shared__ float red[8];
  if (lane == 0) { red[wid * 2] = sum; red[wid * 2 + 1] = sq; }
  __syncthreads();
  if (threadIdx.x == 0) {
    float S = red[0] + red[2] + red[4] + red[6];
    float Q = red[1] + red[3] + red[5] + red[7];
    part[((size_t)c * NSPLIT + s) * 2] = S;
    part[((size_t)c * NSPLIT + s) * 2 + 1] = Q;
  }
}

// combine partials -> folded affine sc = rstd*g, sh = be - mean*rstd*g
// grid = C blocks of 64 threads
__global__ __launch_bounds__(64) void stats_combine(const float* __restrict__ part, int nsplit,
                                                    const float* __restrict__ g,
                                                    const float* __restrict__ be,
                                                    float* __restrict__ sc,
                                                    float* __restrict__ sh) {
  const int c = blockIdx.x;
  double s = 0.0, q = 0.0;
  for (int i = threadIdx.x; i < nsplit; i += 64) {
    s += part[((size_t)c * nsplit + i) * 2];
    q += part[((size_t)c * nsplit + i) * 2 + 1];
  }
  for (int off = 32; off; off >>= 1) {
    s += __shfl_down(s, off);
    q += __shfl_down(q, off);
  }
  if (threadIdx.x == 0) {
    double mean = s / (double)NPC;
    double var = q / (double)NPC - mean * mean;
    float rstd = rsqrtf((float)var + 1e-5f);
    float scl = rstd * g[c];
    sc[c] = scl;
    sh[c] = be[c] - (float)mean * scl;
  }
}

// ---------------------------------------------------------------------------
// shared depthwise 3x3 stride-3 pad-1 conv; optional bn+lrelu on input (AFF)
// ---------------------------------------------------------------------------
template <bool AFF>
__global__ __launch_bounds__(256) void dconv(const float* __restrict__ in,
                                             const float* __restrict__ sc,
                                             const float* __restrict__ sh,
                                             const float* __restrict__ w9,
                                             const float* __restrict__ db,
                                             int Sin, int Sout,
                                             float* __restrict__ out, int total) {
  int idx = blockIdx.x * 256 + threadIdx.x;
  if (idx >= total) return;
  int xx = idx % Sout;
  int t = idx / Sout;
  int yy = t % Sout;
  int pc = t / Sout;
  int c = pc & 31;
  const float* ip = in + (size_t)pc * Sin * Sin;
  float a = AFF ? sc[c] : 1.f;
  float h = AFF ? sh[c] : 0.f;
  float acc = 0.f;
#pragma unroll
  for (int ky = 0; ky < 3; ++ky) {
    int iy = 3 * yy - 1 + ky;
    if (iy < 0 || iy >= Sin) continue;
#pragma unroll
    for (int kx = 0; kx < 3; ++kx) {
      int ix = 3 * xx - 1 + kx;
      if (ix < 0 || ix >= Sin) continue;
      float v = ip[(size_t)iy * Sin + ix];
      if (AFF) { v = v * a + h; v = lrelu01(v); }
      acc = fmaf(v, w9[ky * 3 + kx], acc);
    }
  }
  out[idx] = acc + db[0];
}

// ---------------------------------------------------------------------------
// fused bilinear-upsample(d, Sin->384) + two shared 5x5 convs (pad 2, zero pad
// on z) + per-block partial stats for both outputs.
// grid: (144 tiles of 32x32, 256 planes), block 256.
// ---------------------------------------------------------------------------
__global__ __launch_bounds__(256) void upconv5(const float* __restrict__ d, int Sin, float scale,
                                               const float* __restrict__ wA5,
                                               const float* __restrict__ wB5,
                                               const float* __restrict__ bA,
                                               const float* __restrict__ bB,
                                               float* __restrict__ aout,
                                               float* __restrict__ bout,
                                               float* __restrict__ partA,
                                               float* __restrict__ partB) {
  __shared__ float zt[36][38];
  const int plane = blockIdx.y;
  const int tile = blockIdx.x;
  const int tx = (tile % 12) * 32, ty = (tile / 12) * 32;
  const float* dp = d + (size_t)plane * Sin * Sin;

  for (int i = threadIdx.x; i < 36 * 36; i += 256) {
    int zy = i / 36, zx = i - zy * 36;
    int gy = ty + zy - 2, gx = tx + zx - 2;
    float v = 0.f;
    if (gy >= 0 && gy < WID && gx >= 0 && gx < WID) {
      float sy = (gy + 0.5f) * scale - 0.5f;
      float sx = (gx + 0.5f) * scale - 0.5f;
      float fy0 = floorf(sy), fx0 = floorf(sx);
      float fy = sy - fy0, fx = sx - fx0;
      int iy0 = (int)fy0, ix0 = (int)fx0;
      int iy1 = iy0 + 1 < Sin - 1 ? iy0 + 1 : Sin - 1;
      int ix1 = ix0 + 1 < Sin - 1 ? ix0 + 1 : Sin - 1;
      iy0 = iy0 > 0 ? iy0 : 0;
      ix0 = ix0 > 0 ? ix0 : 0;
      float v00 = dp[(size_t)iy0 * Sin + ix0], v01 = dp[(size_t)iy0 * Sin + ix1];
      float v10 = dp[(size_t)iy1 * Sin + ix0], v11 = dp[(size_t)iy1 * Sin + ix1];
      float top = v00 + fx * (v01 - v00);
      float bot = v10 + fx * (v11 - v10);
      v = top + fy * (bot - top);
    }
    zt[zy][zx] = v;
  }
  float wa[25], wb[25];
#pragma unroll
  for (int k = 0; k < 25; ++k) { wa[k] = wA5[k]; wb[k] = wB5[k]; }
  float ba0 = bA[0], bb0 = bB[0];
  __syncthreads();

  const int lx = threadIdx.x & 31, ly = threadIdx.x >> 5;
  float sum_a = 0.f, sq_a = 0.f, sum_b = 0.f, sq_b = 0.f;
#pragma unroll
  for (int ry = 0; ry < 4; ++ry) {
    int yy = ly + ry * 8;
    float aa = ba0, bb_ = bb0;
#pragma unroll
    for (int dy = 0; dy < 5; ++dy)
#pragma unroll
      for (int dx = 0; dx < 5; ++dx) {
        float zv = zt[yy + dy][lx + dx];
        aa = fmaf(zv, wa[dy * 5 + dx], aa);
        bb_ = fmaf(zv, wb[dy * 5 + dx], bb_);
      }
    size_t o = (size_t)plane * HW + (size_t)(ty + yy) * WID + (tx + lx);
    aout[o] = aa;
    bout[o] = bb_;
    sum_a += aa; sq_a += aa * aa;
    sum_b += bb_; sq_b += bb_ * bb_;
  }
  int lane = threadIdx.x & 63, wid = threadIdx.x >> 6;
  for (int off = 32; off; off >>= 1) {
    sum_a += __shfl_down(sum_a, off); sq_a += __shfl_down(sq_a, off);
    sum_b += __shfl_down(sum_b, off); sq_b += __shfl_down(sq_b, off);
  }
  __shared__ float red[16];
  if (lane == 0) {
    red[wid * 4] = sum_a; red[wid * 4 + 1] = sq_a;
    red[wid * 4 + 2] = sum_b; red[wid * 4 + 3] = sq_b;
  }
  __syncthreads();
  if (threadIdx.x == 0) {
    float SA = red[0] + red[4] + red[8] + red[12];
    float QA = red[1] + red[5] + red[9] + red[13];
    float SB = red[2] + red[6] + red[10] + red[14];
    float QB = red[3] + red[7] + red[11] + red[15];
    int b = plane >> 5, c = plane & 31;
    size_t pi = ((size_t)c * 1152 + (size_t)b * 144 + tile) * 2;
    partA[pi] = SA; partA[pi + 1] = QA;
    partB[pi] = SB; partB[pi + 1] = QB;
  }
}

// ---------------------------------------------------------------------------
// score += lrelu(bn(a_raw)) || lrelu(bn(b_raw)), float4 vectorized
// ---------------------------------------------------------------------------
__global__ __launch_bounds__(256) void accum(const float* __restrict__ araw,
                                             const float* __restrict__ braw,
                                             const float* __restrict__ scA,
                                             const float* __restrict__ shA,
                                             const float* __restrict__ scB,
                                             const float* __restrict__ shB,
                                             float* __restrict__ score) {
  size_t t = (size_t)blockIdx.x * 256 + threadIdx.x;
  size_t idx = t * 4;
  int bc = (int)(idx / HW);
  int p = (int)(idx - (size_t)bc * HW);
  int b = bc >> 6, c = bc & 63;
  const float* src;
  float s, h;
  if (c < 32) {
    src = araw + ((size_t)(b * 32 + c)) * HW + p;
    s = scA[c]; h = shA[c];
  } else {
    int c2 = c - 32;
    src = braw + ((size_t)(b * 32 + c2)) * HW + p;
    s = scB[c2]; h = shB[c2];
  }
  float4 v = *reinterpret_cast<const float4*>(src);
  float4 o = *reinterpret_cast<float4*>(score + idx);
  float u;
  u = v.x * s + h; o.x += lrelu01(u);
  u = v.y * s + h; o.y += lrelu01(u);
  u = v.z * s + h; o.z += lrelu01(u);
  u = v.w * s + h; o.w += lrelu01(u);
  *reinterpret_cast<float4*>(score + idx) = o;
}

// ---------------------------------------------------------------------------
// ft passH: T = horizontal 11-sum of s, where s = affine2(mlrelu(affine1(X)))
// (zero contribution outside width). grid (6, 96, 512), block 256 = 4 rows x 64
// ---------------------------------------------------------------------------
__global__ __launch_bounds__(256) void ft_passH(const float* __restrict__ X,
                                                const float* __restrict__ sc1,
                                                const float* __restrict__ sh1,
                                                const float* __restrict__ sc2,
                                                const float* __restrict__ sh2,
                                                float* __restrict__ T) {
  __shared__ float row[4][80];
  const int plane = blockIdx.z;
  const int c = plane & 63;
  const float a1 = sc1[c], b1 = sh1[c], a2 = sc2[c], b2 = sh2[c];
  const int x0 = blockIdx.x * 64, y0 = blockIdx.y * 4;
  const float* xp = X + (size_t)plane * HW;
  for (int i = threadIdx.x; i < 4 * 74; i += 256) {
    int r = i / 74, ccol = i - r * 74;
    int gx = x0 + ccol - 5;
    float v = 0.f;
    if (gx >= 0 && gx < WID) {
      float u = xp[(size_t)(y0 + r) * WID + gx] * a1 + b1;
      u = mlrelu(u);
      v = u * a2 + b2;
    }
    row[r][ccol] = v;
  }
  __syncthreads();
  int r = threadIdx.x >> 6, xx = threadIdx.x & 63;
  float s = 0.f;
#pragma unroll
  for (int dx = 0; dx < 11; ++dx) s += row[r][xx + dx];
  T[(size_t)plane * HW + (size_t)(y0 + r) * WID + (x0 + xx)] = s;
}

// ---------------------------------------------------------------------------
// ft passV: out = (2*s(X) - vertsum11(T)/121) * fscale, in-place safe on X
// ---------------------------------------------------------------------------
__global__ __launch_bounds__(256) void ft_passV(const float* __restrict__ X,
                                                const float* __restrict__ T,
                                                const float* __restrict__ sc1,
                                                const float* __restrict__ sh1,
                                                const float* __restrict__ sc2,
                                                const float* __restrict__ sh2,
                                                float fscale, float* __restrict__ out) {
  size_t idx = (size_t)blockIdx.x * 256 + threadIdx.x;
  int bc = (int)(idx / HW);
  int p = (int)(idx - (size_t)bc * HW);
  int c = bc & 63;
  int y = p / WID, xx = p - y * WID;
  const float* tp = T + (size_t)bc * HW + xx;
  float acc = 0.f;
#pragma unroll
  for (int dy = -5; dy <= 5; ++dy) {
    int yy = y + dy;
    if (yy >= 0 && yy < WID) acc += tp[(size_t)yy * WID];
  }
  float u = X[idx] * sc1[c] + sh1[c];
  u = mlrelu(u);
  u = u * sc2[c] + sh2[c];
  out[idx] = (2.f * u - acc * (1.f / 121.f)) * fscale;
}

// ---------------------------------------------------------------------------
extern "C" void kernel_launch(void* const* d_in, const int* in_sizes, int n_in,
                              void* d_out, int out_size, void* d_ws, size_t ws_size,
                              hipStream_t stream) {
  const float* x     = (const float*)d_in[0];
  const float* p_w1  = (const float*)d_in[1];
  const float* p_b1  = (const float*)d_in[2];
  const float* p_dw1 = (const float*)d_in[3];
  const float* p_db1 = (const float*)d_in[4];
  const float* p_g1  = (const float*)d_in[5];
  const float* p_be1 = (const float*)d_in[6];
  const float* p_w2  = (const float*)d_in[7];
  const float* p_b2  = (const float*)d_in[8];
  const float* p_dw2 = (const float*)d_in[9];
  const float* p_db2 = (const float*)d_in[10];
  const float* p_g2  = (const float*)d_in[11];
  const float* p_be2 = (const float*)d_in[12];
  const float* d_w   = (const float*)d_in[13];
  const float* d_b   = (const float*)d_in[14];
  const float* ia_w  = (const float*)d_in[15];
  const float* ia_b  = (const float*)d_in[16];
  const float* ia_g  = (const float*)d_in[17];
  const float* ia_be = (const float*)d_in[18];
  const float* ib_w  = (const float*)d_in[19];
  const float* ib_b  = (const float*)d_in[20];
  const float* ib_g  = (const float*)d_in[21];
  const float* ib_be = (const float*)d_in[22];
  const float* f_g1  = (const float*)d_in[23];
  const float* f_be1 = (const float*)d_in[24];
  const float* f_g2  = (const float*)d_in[25];
  const float* f_be2 = (const float*)d_in[26];
  float* out = (float*)d_out;
  float* ws = (float*)d_ws;

  const size_t SLOT = 37748736;  // 8*32*384*384 floats
  float* slotA = ws;
  float* slotB = ws + SLOT;
  float* xm = ws + 2 * SLOT;              // 3,538,944
  float* dd1 = xm + 3538944;              // 4,194,304
  float* dd2 = dd1 + 4194304;             // 473,344
  float* dd3 = dd2 + 473344;              // 57,600
  float* dd4 = dd3 + 57600;               // 6,400
  float* dd5 = dd4 + 6400;                // 1,024
  float* partA = dd5 + 1024;              // 73,728
  float* partB = partA + 73728;           // 73,728
  float* partG = partB + 73728;           // 8,192
  float* st = partG + 8192;               // 512 floats of folded affines
  float* P1SC = st, *P1SH = st + 32, *P2SC = st + 64, *P2SH = st + 96;
  float* ASC = st + 128, *ASH = st + 160, *BSC = st + 192, *BSH = st + 224;
  float* F1SC = st + 256, *F1SH = st + 320, *F2SC = st + 384, *F2SH = st + 448;

  hipMemsetAsync(d_out, 0, (size_t)out_size * sizeof(float), stream);

  // mode filter
  mode_kernel<<<dim3(6, 24, 24), 256, 0, stream>>>(x, xm);

  // prepare
  prep_conv1<<<4608, 256, 0, stream>>>(xm, p_w1, p_b1, p_dw1, p_db1, slotA);
  stats_partial<0><<<32 * NSPLIT, 256, 0, stream>>>(slotA, nullptr, nullptr, partG, 32);
  stats_combine<<<32, 64, 0, stream>>>(partG, NSPLIT, p_g1, p_be1, P1SC, P1SH);
  prep_conv2<<<4608, 256, 0, stream>>>(slotA, P1SC, P1SH, p_w2, p_b2, p_dw2, p_db2, slotB);
  stats_partial<0><<<32 * NSPLIT, 256, 0, stream>>>(slotB, nullptr, nullptr, partG, 32);
  stats_combine<<<32, 64, 0, stream>>>(partG, NSPLIT, p_g2, p_be2, P2SC, P2SH);

  // d1 = shared 3x3 stride3 conv of h = lrelu(bn(t2)) (affine applied on read)
  dconv<true><<<(8 * 32 * 128 * 128) / 256, 256, 0, stream>>>(
      slotB, P2SC, P2SH, d_w, d_b, 384, 128, dd1, 8 * 32 * 128 * 128);

  float* dbuf[5] = {dd1, dd2, dd3, dd4, dd5};
  const int S[5] = {128, 43, 15, 5, 2};
  for (int it = 0; it < 5; ++it) {
    upconv5<<<dim3(144, 256), 256, 0, stream>>>(dbuf[it], S[it], (float)S[it] / 384.0f,
                                                ia_w, ib_w, ia_b, ib_b,
                                                slotA, slotB, partA, partB);
    stats_combine<<<32, 64, 0, stream>>>(partA, 1152, ia_g, ia_be, ASC, ASH);
    stats_combine<<<32, 64, 0, stream>>>(partB, 1152, ib_g, ib_be, BSC, BSH);
    accum<<<73728, 256, 0, stream>>>(slotA, slotB, ASC, ASH, BSC, BSH, out);
    if (it < 4) {
      int so = S[it + 1];
      int tot = 8 * 32 * so * so;
      dconv<false><<<(tot + 255) / 256, 256, 0, stream>>>(
          dbuf[it], nullptr, nullptr, d_w, d_b, S[it], so, dbuf[it + 1], tot);
    }
  }

  // ft chain x3 (in-place on d_out; T = ws slots A+B)
  float* T = ws;  // 2*SLOT floats
  for (int k = 0; k < 3; ++k) {
    stats_partial<0><<<64 * NSPLIT, 256, 0, stream>>>(out, nullptr, nullptr, partG, 64);
    stats_combine<<<64, 64, 0, stream>>>(partG, NSPLIT, f_g1, f_be1, F1SC, F1SH);
    stats_partial<1><<<64 * NSPLIT, 256, 0, stream>>>(out, F1SC, F1SH, partG, 64);
    stats_combine<<<64, 64, 0, stream>>>(partG, NSPLIT, f_g2, f_be2, F2SC, F2SH);
    ft_passH<<<dim3(6, 96, 512), 256, 0, stream>>>(out, F1SC, F1SH, F2SC, F2SH, T);
    float fs = (k == 2) ? 0.2f : 1.0f;
    ft_passV<<<294912, 256, 0, stream>>>(out, T, F1SC, F1SH, F2SC, F2SH, fs, out);
  }
}

// Round 2
// 2464.729 us; speedup vs baseline: 2.3102x; 2.3102x over previous
//
#include <hip/hip_runtime.h>

#define HW 147456
#define WID 384
#define NB 8
#define NPC 1179648   // per-channel element count = 8*384*384
#define HW4 36864     // HW/4

static __device__ __forceinline__ float lrelu01(float v) { return v >= 0.f ? v : 0.01f * v; }
static __device__ __forceinline__ float mlrelu(float v) { return v > 0.1f ? 0.1f + 0.7f * (v - 0.1f) : v; }

// ---------------------------------------------------------------------------
// Mode pool (unchanged from round 1; correct & cheap)
// ---------------------------------------------------------------------------
__global__ __launch_bounds__(256) void mode_kernel(const float* __restrict__ x,
                                                   float* __restrict__ xm) {
  __shared__ unsigned char qt[26 * 76];
  __shared__ unsigned int cc[16 * 5 * 76];
  const int plane = blockIdx.z;
  const int x0 = blockIdx.x * 64;
  const int y0 = blockIdx.y * 16;
  const float* xp = x + (size_t)plane * HW;

  for (int i = threadIdx.x; i < 26 * 76; i += 256) {
    int r = i / 76, ccol = i - r * 76;
    int gy = y0 + r - 5, gx = x0 + ccol - 5;
    unsigned char q = 0;
    if (ccol < 74 && gy >= 0 && gy < WID && gx >= 0 && gx < WID) {
      float v = xp[gy * WID + gx];
      int qi = (int)rintf(v * 15.9375f);
      qi = qi < 0 ? 0 : (qi > 16 ? 16 : qi);
      q = (unsigned char)qi;
    }
    qt[i] = q;
  }
  __syncthreads();

  for (int i = threadIdx.x; i < 16 * 74; i += 256) {
    int yy = i / 74, col = i - yy * 74;
    unsigned int w0 = 0, w1 = 0, w2 = 0, w3 = 0, w4 = 0;
#pragma unroll
    for (int dy = 0; dy < 11; ++dy) {
      int q = qt[(yy + dy) * 76 + col];
      unsigned int inc = 1u << ((q & 3) << 3);
      int wsel = q >> 2;
      w0 += (wsel == 0) ? inc : 0u;
      w1 += (wsel == 1) ? inc : 0u;
      w2 += (wsel == 2) ? inc : 0u;
      w3 += (wsel == 3) ? inc : 0u;
      w4 += (wsel == 4) ? inc : 0u;
    }
    cc[(yy * 5 + 0) * 76 + col] = w0;
    cc[(yy * 5 + 1) * 76 + col] = w1;
    cc[(yy * 5 + 2) * 76 + col] = w2;
    cc[(yy * 5 + 3) * 76 + col] = w3;
    cc[(yy * 5 + 4) * 76 + col] = w4;
  }
  __syncthreads();

  for (int i = threadIdx.x; i < 16 * 64; i += 256) {
    int yy = i / 64, xx = i - yy * 64;
    unsigned int s0 = 0, s1 = 0, s2 = 0, s3 = 0, s4 = 0;
#pragma unroll
    for (int dx = 0; dx < 11; ++dx) {
      int col = xx + dx;
      s0 += cc[(yy * 5 + 0) * 76 + col];
      s1 += cc[(yy * 5 + 1) * 76 + col];
      s2 += cc[(yy * 5 + 2) * 76 + col];
      s3 += cc[(yy * 5 + 3) * 76 + col];
      s4 += cc[(yy * 5 + 4) * 76 + col];
    }
    unsigned int words[5] = {s0, s1, s2, s3, s4};
    int best = 0;
    unsigned int bc = s0 & 0xffu;
#pragma unroll
    for (int bin = 1; bin < 17; ++bin) {
      unsigned int cnt = (words[bin >> 2] >> ((bin & 3) * 8)) & 0xffu;
      if (cnt > bc) { bc = cnt; best = bin; }
    }
    xm[(size_t)plane * HW + (size_t)(y0 + yy) * WID + (x0 + xx)] = best * 0.0625f;
  }
}

// ---------------------------------------------------------------------------
// prepare layer 1: 1x1 conv (3->32) folded with depthwise scale; fused stats.
// grid 1152 blocks, each thread 4 pixels.
// ---------------------------------------------------------------------------
__global__ __launch_bounds__(256) void prep_conv1_f(const float* __restrict__ xm,
                                                    const float* __restrict__ w1,
                                                    const float* __restrict__ b1,
                                                    const float* __restrict__ dw1,
                                                    const float* __restrict__ db1,
                                                    float* __restrict__ t1,
                                                    float* __restrict__ part) {
  __shared__ float fw[32][4];
  __shared__ float wred[8][32];
  if (threadIdx.x < 32) {
    int o = threadIdx.x;
    float dw = dw1[o];
    fw[o][0] = w1[o * 3] * dw;
    fw[o][1] = w1[o * 3 + 1] * dw;
    fw[o][2] = w1[o * 3 + 2] * dw;
    fw[o][3] = b1[o] * dw + db1[o];
  }
  __syncthreads();
  float sv[32], sq[32];
#pragma unroll
  for (int o = 0; o < 32; ++o) { sv[o] = 0.f; sq[o] = 0.f; }
  int p0 = blockIdx.x * 1024 + threadIdx.x;
#pragma unroll
  for (int q = 0; q < 4; ++q) {
    int p = p0 + q * 256;
    int b = p / HW, pp = p - b * HW;
    const float* xb = xm + (size_t)b * 3 * HW + pp;
    float x0 = xb[0], x1 = xb[HW], x2 = xb[2 * HW];
    float* tb = t1 + (size_t)b * 32 * HW + pp;
#pragma unroll
    for (int o = 0; o < 32; ++o) {
      float v = fmaf(x0, fw[o][0], fmaf(x1, fw[o][1], fmaf(x2, fw[o][2], fw[o][3])));
      tb[(size_t)o * HW] = v;
      sv[o] += v;
      sq[o] += v * v;
    }
  }
  int lane = threadIdx.x & 63, wid = threadIdx.x >> 6;
#pragma unroll
  for (int o = 0; o < 32; ++o) {
    float a = sv[o], qq = sq[o];
    for (int off = 32; off; off >>= 1) {
      a += __shfl_down(a, off);
      qq += __shfl_down(qq, off);
    }
    if (lane == 0) { wred[wid][o] = a; wred[wid + 4][o] = qq; }
  }
  __syncthreads();
  if (threadIdx.x < 32) {
    int o = threadIdx.x;
    float S = wred[0][o] + wred[1][o] + wred[2][o] + wred[3][o];
    float Q = wred[4][o] + wred[5][o] + wred[6][o] + wred[7][o];
    part[((size_t)o * 1152 + blockIdx.x) * 2] = S;
    part[((size_t)o * 1152 + blockIdx.x) * 2 + 1] = Q;
  }
}

// ---------------------------------------------------------------------------
// prepare layer 2: bn1+lrelu on read, 32x32 matmul (weights folded with dw2),
// 4 pixels/thread to amortize weight reads. No fused stats (register budget).
// ---------------------------------------------------------------------------
__global__ __launch_bounds__(256) void prep_conv2_f(const float* __restrict__ t1,
                                                    const float* __restrict__ sc1,
                                                    const float* __restrict__ sh1,
                                                    const float* __restrict__ w2,
                                                    const float* __restrict__ b2,
                                                    const float* __restrict__ dw2,
                                                    const float* __restrict__ db2,
                                                    float* __restrict__ t2) {
  __shared__ float wl[1024];
  __shared__ float cb[32][3];
  for (int i = threadIdx.x; i < 1024; i += 256) {
    int o = i >> 5;
    wl[i] = w2[i] * dw2[o];
  }
  if (threadIdx.x < 32) {
    int c = threadIdx.x;
    cb[c][0] = sc1[c];
    cb[c][1] = sh1[c];
    cb[c][2] = b2[c] * dw2[c] + db2[c];
  }
  __syncthreads();
  int p0 = blockIdx.x * 1024 + threadIdx.x;
  int b = p0 / HW;  // 1024-aligned blocks never straddle a batch boundary? HW=147456=144*1024 -> yes, aligned.
  int pp0 = p0 - b * HW;
  const float* tb = t1 + (size_t)b * 32 * HW + pp0;
  float* ob = t2 + (size_t)b * 32 * HW + pp0;
  float h[4][32];
#pragma unroll
  for (int q = 0; q < 4; ++q) {
#pragma unroll
    for (int c = 0; c < 32; ++c) {
      float v = tb[(size_t)c * HW + q * 256];
      v = fmaf(v, cb[c][0], cb[c][1]);
      h[q][c] = lrelu01(v);
    }
  }
  const float4* wl4 = reinterpret_cast<const float4*>(wl);
  for (int o = 0; o < 32; ++o) {
    float bias = cb[o][2];
    float a0 = bias, a1 = bias, a2 = bias, a3 = bias;
#pragma unroll
    for (int c4 = 0; c4 < 8; ++c4) {
      float4 w4 = wl4[o * 8 + c4];
      int c = c4 * 4;
      a0 = fmaf(h[0][c], w4.x, a0); a1 = fmaf(h[1][c], w4.x, a1);
      a2 = fmaf(h[2][c], w4.x, a2); a3 = fmaf(h[3][c], w4.x, a3);
      a0 = fmaf(h[0][c + 1], w4.y, a0); a1 = fmaf(h[1][c + 1], w4.y, a1);
      a2 = fmaf(h[2][c + 1], w4.y, a2); a3 = fmaf(h[3][c + 1], w4.y, a3);
      a0 = fmaf(h[0][c + 2], w4.z, a0); a1 = fmaf(h[1][c + 2], w4.z, a1);
      a2 = fmaf(h[2][c + 2], w4.z, a2); a3 = fmaf(h[3][c + 2], w4.z, a3);
      a0 = fmaf(h[0][c + 3], w4.w, a0); a1 = fmaf(h[1][c + 3], w4.w, a1);
      a2 = fmaf(h[2][c + 3], w4.w, a2); a3 = fmaf(h[3][c + 3], w4.w, a3);
    }
    float* op = ob + (size_t)o * HW;
    op[0] = a0; op[256] = a1; op[512] = a2; op[768] = a3;
  }
}

// ---------------------------------------------------------------------------
// vectorized per-channel raw stats: layout [b][C][HW], float4.
// grid = C*64 blocks.
// ---------------------------------------------------------------------------
__global__ __launch_bounds__(256) void stats_raw(const float4* __restrict__ X, int C,
                                                 float* __restrict__ part) {
  int c = blockIdx.x >> 6, s = blockIdx.x & 63;
  float sum = 0.f, sq = 0.f;
  int fi = s * 4608 + threadIdx.x;
#pragma unroll 2
  for (int it = 0; it < 18; ++it, fi += 256) {
    int b = fi / HW4, p4 = fi - b * HW4;
    float4 v = X[(size_t)(b * C + c) * HW4 + p4];
    sum += v.x + v.y + v.z + v.w;
    sq += v.x * v.x + v.y * v.y + v.z * v.z + v.w * v.w;
  }
  int lane = threadIdx.x & 63, wid = threadIdx.x >> 6;
  for (int off = 32; off; off >>= 1) {
    sum += __shfl_down(sum, off);
    sq += __shfl_down(sq, off);
  }
  __shared__ float red[8];
  if (lane == 0) { red[wid * 2] = sum; red[wid * 2 + 1] = sq; }
  __syncthreads();
  if (threadIdx.x == 0) {
    part[((size_t)c * 64 + s) * 2] = red[0] + red[2] + red[4] + red[6];
    part[((size_t)c * 64 + s) * 2 + 1] = red[1] + red[3] + red[5] + red[7];
  }
}

// mlrelu(affine1(x)) stats, C=64, float4. grid = 64*64.
__global__ __launch_bounds__(256) void stats_mlrelu(const float4* __restrict__ X,
                                                    const float* __restrict__ sc1,
                                                    const float* __restrict__ sh1,
                                                    float* __restrict__ part) {
  int c = blockIdx.x >> 6, s = blockIdx.x & 63;
  float a1 = sc1[c], b1 = sh1[c];
  float sum = 0.f, sq = 0.f;
  int fi = s * 4608 + threadIdx.x;
#pragma unroll 2
  for (int it = 0; it < 18; ++it, fi += 256) {
    int b = fi / HW4, p4 = fi - b * HW4;
    float4 v = X[(size_t)(b * 64 + c) * HW4 + p4];
    float u;
    u = mlrelu(fmaf(v.x, a1, b1)); sum += u; sq += u * u;
    u = mlrelu(fmaf(v.y, a1, b1)); sum += u; sq += u * u;
    u = mlrelu(fmaf(v.z, a1, b1)); sum += u; sq += u * u;
    u = mlrelu(fmaf(v.w, a1, b1)); sum += u; sq += u * u;
  }
  int lane = threadIdx.x & 63, wid = threadIdx.x >> 6;
  for (int off = 32; off; off >>= 1) {
    sum += __shfl_down(sum, off);
    sq += __shfl_down(sq, off);
  }
  __shared__ float red[8];
  if (lane == 0) { red[wid * 2] = sum; red[wid * 2 + 1] = sq; }
  __syncthreads();
  if (threadIdx.x == 0) {
    part[((size_t)c * 64 + s) * 2] = red[0] + red[2] + red[4] + red[6];
    part[((size_t)c * 64 + s) * 2 + 1] = red[1] + red[3] + red[5] + red[7];
  }
}

// combine partials -> folded affine sc = rstd*g, sh = be - mean*rstd*g
__global__ __launch_bounds__(64) void stats_combine(const float* __restrict__ part, int nsplit,
                                                    const float* __restrict__ g,
                                                    const float* __restrict__ be,
                                                    float* __restrict__ sc,
                                                    float* __restrict__ sh) {
  const int c = blockIdx.x;
  double s = 0.0, q = 0.0;
  for (int i = threadIdx.x; i < nsplit; i += 64) {
    s += part[((size_t)c * nsplit + i) * 2];
    q += part[((size_t)c * nsplit + i) * 2 + 1];
  }
  for (int off = 32; off; off >>= 1) {
    s += __shfl_down(s, off);
    q += __shfl_down(q, off);
  }
  if (threadIdx.x == 0) {
    double mean = s / (double)NPC;
    double var = q / (double)NPC - mean * mean;
    float rstd = rsqrtf((float)var + 1e-5f);
    float scl = rstd * g[c];
    sc[c] = scl;
    sh[c] = be[c] - (float)mean * scl;
  }
}

// ---------------------------------------------------------------------------
// shared depthwise 3x3 stride-3 pad-1 conv; optional bn+lrelu on input (AFF)
// ---------------------------------------------------------------------------
template <bool AFF>
__global__ __launch_bounds__(256) void dconv(const float* __restrict__ in,
                                             const float* __restrict__ sc,
                                             const float* __restrict__ sh,
                                             const float* __restrict__ w9,
                                             const float* __restrict__ db,
                                             int Sin, int Sout,
                                             float* __restrict__ out, int total) {
  int idx = blockIdx.x * 256 + threadIdx.x;
  if (idx >= total) return;
  int xx = idx % Sout;
  int t = idx / Sout;
  int yy = t % Sout;
  int pc = t / Sout;
  int c = pc & 31;
  const float* ip = in + (size_t)pc * Sin * Sin;
  float a = AFF ? sc[c] : 1.f;
  float h = AFF ? sh[c] : 0.f;
  float acc = 0.f;
#pragma unroll
  for (int ky = 0; ky < 3; ++ky) {
    int iy = 3 * yy - 1 + ky;
    if (iy < 0 || iy >= Sin) continue;
#pragma unroll
    for (int kx = 0; kx < 3; ++kx) {
      int ix = 3 * xx - 1 + kx;
      if (ix < 0 || ix >= Sin) continue;
      float v = ip[(size_t)iy * Sin + ix];
      if (AFF) { v = v * a + h; v = lrelu01(v); }
      acc = fmaf(v, w9[ky * 3 + kx], acc);
    }
  }
  out[idx] = acc + db[0];
}

// ---------------------------------------------------------------------------
// fused bilinear-upsample + two shared 5x5 convs. MODE 0: stats only;
// MODE 1: apply (write, first level); MODE 2: apply (accumulate);
// MODE 3: apply (accumulate) + fused raw stats of final score.
// grid (144, 256), block 256: thread = (row 0..31, colgroup 0..7 of 4 cols).
// ---------------------------------------------------------------------------
template <int MODE>
__global__ __launch_bounds__(256) void upconv_k(const float* __restrict__ d, int Sin, float scale,
                                                const float* __restrict__ wA5,
                                                const float* __restrict__ wB5,
                                                const float* __restrict__ bA,
                                                const float* __restrict__ bB,
                                                const float* __restrict__ ASC,
                                                const float* __restrict__ ASH,
                                                const float* __restrict__ BSC,
                                                const float* __restrict__ BSH,
                                                float* __restrict__ outp,
                                                float* __restrict__ partA,
                                                float* __restrict__ partB,
                                                float* __restrict__ partF) {
  __shared__ float zt[36 * 40];
  __shared__ float red[16];
  const int plane = blockIdx.y;
  const int tile = blockIdx.x;
  const int tx = (tile % 12) * 32, ty = (tile / 12) * 32;
  const float* dp = d + (size_t)plane * Sin * Sin;

  for (int i = threadIdx.x; i < 36 * 36; i += 256) {
    int zy = i / 36, zx = i - zy * 36;
    int gy = ty + zy - 2, gx = tx + zx - 2;
    float v = 0.f;
    if (gy >= 0 && gy < WID && gx >= 0 && gx < WID) {
      float sy = (gy + 0.5f) * scale - 0.5f;
      float sx = (gx + 0.5f) * scale - 0.5f;
      float fy0 = floorf(sy), fx0 = floorf(sx);
      float fy = sy - fy0, fx = sx - fx0;
      int iy0 = (int)fy0, ix0 = (int)fx0;
      int iy1 = iy0 + 1 < Sin - 1 ? iy0 + 1 : Sin - 1;
      int ix1 = ix0 + 1 < Sin - 1 ? ix0 + 1 : Sin - 1;
      iy0 = iy0 > 0 ? iy0 : 0;
      ix0 = ix0 > 0 ? ix0 : 0;
      float v00 = dp[(size_t)iy0 * Sin + ix0], v01 = dp[(size_t)iy0 * Sin + ix1];
      float v10 = dp[(size_t)iy1 * Sin + ix0], v11 = dp[(size_t)iy1 * Sin + ix1];
      float top = v00 + fx * (v01 - v00);
      float bot = v10 + fx * (v11 - v10);
      v = top + fy * (bot - top);
    }
    zt[zy * 40 + zx] = v;
  }
  float wa[25], wb[25];
#pragma unroll
  for (int k = 0; k < 25; ++k) { wa[k] = wA5[k]; wb[k] = wB5[k]; }
  float ba0 = bA[0], bb0 = bB[0];
  __syncthreads();

  const int row = threadIdx.x >> 3;
  const int g = threadIdx.x & 7;
  float aa0 = ba0, aa1 = ba0, aa2 = ba0, aa3 = ba0;
  float eb0 = bb0, eb1 = bb0, eb2 = bb0, eb3 = bb0;
#pragma unroll
  for (int dy = 0; dy < 5; ++dy) {
    const float* zr = &zt[(row + dy) * 40 + g * 4];
    float z[8];
#pragma unroll
    for (int j = 0; j < 8; ++j) z[j] = zr[j];
#pragma unroll
    for (int dx = 0; dx < 5; ++dx) {
      float wva = wa[dy * 5 + dx], wvb = wb[dy * 5 + dx];
      aa0 = fmaf(z[dx], wva, aa0);
      aa1 = fmaf(z[dx + 1], wva, aa1);
      aa2 = fmaf(z[dx + 2], wva, aa2);
      aa3 = fmaf(z[dx + 3], wva, aa3);
      eb0 = fmaf(z[dx], wvb, eb0);
      eb1 = fmaf(z[dx + 1], wvb, eb1);
      eb2 = fmaf(z[dx + 2], wvb, eb2);
      eb3 = fmaf(z[dx + 3], wvb, eb3);
    }
  }
  const int b = plane >> 5, c = plane & 31;
  const int lane = threadIdx.x & 63, wid = threadIdx.x >> 6;

  if (MODE == 0) {
    float sa = aa0 + aa1 + aa2 + aa3;
    float qa = aa0 * aa0 + aa1 * aa1 + aa2 * aa2 + aa3 * aa3;
    float sb = eb0 + eb1 + eb2 + eb3;
    float qb = eb0 * eb0 + eb1 * eb1 + eb2 * eb2 + eb3 * eb3;
    for (int off = 32; off; off >>= 1) {
      sa += __shfl_down(sa, off); qa += __shfl_down(qa, off);
      sb += __shfl_down(sb, off); qb += __shfl_down(qb, off);
    }
    if (lane == 0) {
      red[wid * 4] = sa; red[wid * 4 + 1] = qa;
      red[wid * 4 + 2] = sb; red[wid * 4 + 3] = qb;
    }
    __syncthreads();
    if (threadIdx.x == 0) {
      size_t pi = ((size_t)c * 1152 + (size_t)b * 144 + tile) * 2;
      partA[pi] = red[0] + red[4] + red[8] + red[12];
      partA[pi + 1] = red[1] + red[5] + red[9] + red[13];
      partB[pi] = red[2] + red[6] + red[10] + red[14];
      partB[pi + 1] = red[3] + red[7] + red[11] + red[15];
    }
  } else {
    float as = ASC[c], ah = ASH[c], bs = BSC[c], bh = BSH[c];
    float4 xa, xb;
    xa.x = lrelu01(fmaf(aa0, as, ah));
    xa.y = lrelu01(fmaf(aa1, as, ah));
    xa.z = lrelu01(fmaf(aa2, as, ah));
    xa.w = lrelu01(fmaf(aa3, as, ah));
    xb.x = lrelu01(fmaf(eb0, bs, bh));
    xb.y = lrelu01(fmaf(eb1, bs, bh));
    xb.z = lrelu01(fmaf(eb2, bs, bh));
    xb.w = lrelu01(fmaf(eb3, bs, bh));
    size_t po = (size_t)(b * 64 + c) * HW + (size_t)(ty + row) * WID + tx + g * 4;
    float* pA = outp + po;
    float* pB = outp + po + (size_t)32 * HW;
    if (MODE == 1) {
      *reinterpret_cast<float4*>(pA) = xa;
      *reinterpret_cast<float4*>(pB) = xb;
    } else {
      float4 oa = *reinterpret_cast<const float4*>(pA);
      float4 ob = *reinterpret_cast<const float4*>(pB);
      oa.x += xa.x; oa.y += xa.y; oa.z += xa.z; oa.w += xa.w;
      ob.x += xb.x; ob.y += xb.y; ob.z += xb.z; ob.w += xb.w;
      *reinterpret_cast<float4*>(pA) = oa;
      *reinterpret_cast<float4*>(pB) = ob;
      if (MODE == 3) {
        float sa = oa.x + oa.y + oa.z + oa.w;
        float qa = oa.x * oa.x + oa.y * oa.y + oa.z * oa.z + oa.w * oa.w;
        float sb = ob.x + ob.y + ob.z + ob.w;
        float qb = ob.x * ob.x + ob.y * ob.y + ob.z * ob.z + ob.w * ob.w;
        for (int off = 32; off; off >>= 1) {
          sa += __shfl_down(sa, off); qa += __shfl_down(qa, off);
          sb += __shfl_down(sb, off); qb += __shfl_down(qb, off);
        }
        if (lane == 0) {
          red[wid * 4] = sa; red[wid * 4 + 1] = qa;
          red[wid * 4 + 2] = sb; red[wid * 4 + 3] = qb;
        }
        __syncthreads();
        if (threadIdx.x == 0) {
          size_t piA = ((size_t)c * 1152 + (size_t)b * 144 + tile) * 2;
          size_t piB = ((size_t)(c + 32) * 1152 + (size_t)b * 144 + tile) * 2;
          partF[piA] = red[0] + red[4] + red[8] + red[12];
          partF[piA + 1] = red[1] + red[5] + red[9] + red[13];
          partF[piB] = red[2] + red[6] + red[10] + red[14];
          partF[piB + 1] = red[3] + red[7] + red[11] + red[15];
        }
      }
    }
  }
}

// ---------------------------------------------------------------------------
// fused ft pass: s = affine2(mlrelu(affine1(X))) on a 64x64 tile (+5 halo,
// zero outside image), separable 11x11 box via LDS, out = (2s - box/121)*fscale.
// Optional fused raw stats of output (part != nullptr, nsplit=288).
// grid (36 tiles, 512 planes), block 256.
// ---------------------------------------------------------------------------
__global__ __launch_bounds__(256) void ft_fused(const float* __restrict__ src,
                                                const float* __restrict__ F1SC,
                                                const float* __restrict__ F1SH,
                                                const float* __restrict__ F2SC,
                                                const float* __restrict__ F2SH,
                                                float* __restrict__ dst, float fscale,
                                                float* __restrict__ part) {
  __shared__ float sl[74 * 80];
  __shared__ float Hl[74 * 64];
  __shared__ float red[8];
  const int tile = blockIdx.x;
  const int plane = blockIdx.y;
  const int b = plane >> 6, c = plane & 63;
  const int tx = (tile % 6) * 64, ty = (tile / 6) * 64;
  const float a1 = F1SC[c], b1 = F1SH[c], a2 = F2SC[c], b2 = F2SH[c];
  const float* sp = src + (size_t)plane * HW;

  for (int i = threadIdx.x; i < 74 * 20; i += 256) {
    int r = i / 20, k = i - r * 20;
    int gy = ty + r - 5, gx = tx + k * 4 - 8;
    float4 sv = {0.f, 0.f, 0.f, 0.f};
    if (gy >= 0 && gy < WID && gx >= 0 && gx < WID) {
      float4 v = *reinterpret_cast<const float4*>(sp + (size_t)gy * WID + gx);
      sv.x = fmaf(mlrelu(fmaf(v.x, a1, b1)), a2, b2);
      sv.y = fmaf(mlrelu(fmaf(v.y, a1, b1)), a2, b2);
      sv.z = fmaf(mlrelu(fmaf(v.z, a1, b1)), a2, b2);
      sv.w = fmaf(mlrelu(fmaf(v.w, a1, b1)), a2, b2);
    }
    *reinterpret_cast<float4*>(&sl[r * 80 + k * 4]) = sv;
  }
  __syncthreads();

  for (int i = threadIdx.x; i < 74 * 16; i += 256) {
    int r = i >> 4, g = i & 15;
    const float* s0 = &sl[r * 80 + g * 4 + 3];
    float v[14];
#pragma unroll
    for (int j = 0; j < 14; ++j) v[j] = s0[j];
    float h0 = v[0] + v[1] + v[2] + v[3] + v[4] + v[5] + v[6] + v[7] + v[8] + v[9] + v[10];
    float h1 = h0 - v[0] + v[11];
    float h2 = h1 - v[1] + v[12];
    float h3 = h2 - v[2] + v[13];
    float4 hh = {h0, h1, h2, h3};
    *reinterpret_cast<float4*>(&Hl[r * 64 + g * 4]) = hh;
  }
  __syncthreads();

  const int g = threadIdx.x & 15, ly = threadIdx.x >> 4;
  const int y0 = ly * 4;
  const float4* H4 = reinterpret_cast<const float4*>(Hl);
  float4 acc = H4[y0 * 16 + g];
#pragma unroll
  for (int dy = 1; dy < 11; ++dy) {
    float4 t = H4[(y0 + dy) * 16 + g];
    acc.x += t.x; acc.y += t.y; acc.z += t.z; acc.w += t.w;
  }
  float sum = 0.f, sq = 0.f;
  float* dpo = dst + (size_t)plane * HW;
#pragma unroll
  for (int ry = 0; ry < 4; ++ry) {
    int y = y0 + ry;
    if (ry) {
      float4 ta = H4[(y + 10) * 16 + g];
      float4 tb = H4[(y - 1) * 16 + g];
      acc.x += ta.x - tb.x; acc.y += ta.y - tb.y;
      acc.z += ta.z - tb.z; acc.w += ta.w - tb.w;
    }
    float4 sc4 = *reinterpret_cast<const float4*>(&sl[(y + 5) * 80 + g * 4 + 8]);
    float4 o;
    o.x = (2.f * sc4.x - acc.x * (1.f / 121.f)) * fscale;
    o.y = (2.f * sc4.y - acc.y * (1.f / 121.f)) * fscale;
    o.z = (2.f * sc4.z - acc.z * (1.f / 121.f)) * fscale;
    o.w = (2.f * sc4.w - acc.w * (1.f / 121.f)) * fscale;
    *reinterpret_cast<float4*>(dpo + (size_t)(ty + y) * WID + tx + g * 4) = o;
    sum += o.x + o.y + o.z + o.w;
    sq += o.x * o.x + o.y * o.y + o.z * o.z + o.w * o.w;
  }
  if (part) {
    int lane = threadIdx.x & 63, wid = threadIdx.x >> 6;
    for (int off = 32; off; off >>= 1) {
      sum += __shfl_down(sum, off);
      sq += __shfl_down(sq, off);
    }
    if (lane == 0) { red[wid * 2] = sum; red[wid * 2 + 1] = sq; }
    __syncthreads();
    if (threadIdx.x == 0) {
      size_t pi = ((size_t)c * 288 + (size_t)b * 36 + tile) * 2;
      part[pi] = red[0] + red[2] + red[4] + red[6];
      part[pi + 1] = red[1] + red[3] + red[5] + red[7];
    }
  }
}

// ---------------------------------------------------------------------------
// fallback ft passes (used for last hop only if ws lacks a second big buffer)
// ---------------------------------------------------------------------------
__global__ __launch_bounds__(256) void ft_passH(const float* __restrict__ X,
                                                const float* __restrict__ sc1,
                                                const float* __restrict__ sh1,
                                                const float* __restrict__ sc2,
                                                const float* __restrict__ sh2,
                                                float* __restrict__ T) {
  __shared__ float row[4][80];
  const int plane = blockIdx.z;
  const int c = plane & 63;
  const float a1 = sc1[c], b1 = sh1[c], a2 = sc2[c], b2 = sh2[c];
  const int x0 = blockIdx.x * 64, y0 = blockIdx.y * 4;
  const float* xp = X + (size_t)plane * HW;
  for (int i = threadIdx.x; i < 4 * 74; i += 256) {
    int r = i / 74, ccol = i - r * 74;
    int gx = x0 + ccol - 5;
    float v = 0.f;
    if (gx >= 0 && gx < WID) {
      float u = xp[(size_t)(y0 + r) * WID + gx] * a1 + b1;
      u = mlrelu(u);
      v = u * a2 + b2;
    }
    row[r][ccol] = v;
  }
  __syncthreads();
  int r = threadIdx.x >> 6, xx = threadIdx.x & 63;
  float s = 0.f;
#pragma unroll
  for (int dx = 0; dx < 11; ++dx) s += row[r][xx + dx];
  T[(size_t)plane * HW + (size_t)(y0 + r) * WID + (x0 + xx)] = s;
}

__global__ __launch_bounds__(256) void ft_passV(const float* __restrict__ X,
                                                const float* __restrict__ T,
                                                const float* __restrict__ sc1,
                                                const float* __restrict__ sh1,
                                                const float* __restrict__ sc2,
                                                const float* __restrict__ sh2,
                                                float fscale, float* __restrict__ out) {
  size_t idx = (size_t)blockIdx.x * 256 + threadIdx.x;
  int bc = (int)(idx / HW);
  int p = (int)(idx - (size_t)bc * HW);
  int c = bc & 63;
  int y = p / WID, xx = p - y * WID;
  const float* tp = T + (size_t)bc * HW + xx;
  float acc = 0.f;
#pragma unroll
  for (int dy = -5; dy <= 5; ++dy) {
    int yy = y + dy;
    if (yy >= 0 && yy < WID) acc += tp[(size_t)yy * WID];
  }
  float u = X[idx] * sc1[c] + sh1[c];
  u = mlrelu(u);
  u = u * sc2[c] + sh2[c];
  out[idx] = (2.f * u - acc * (1.f / 121.f)) * fscale;
}

// ---------------------------------------------------------------------------
extern "C" void kernel_launch(void* const* d_in, const int* in_sizes, int n_in,
                              void* d_out, int out_size, void* d_ws, size_t ws_size,
                              hipStream_t stream) {
  const float* x     = (const float*)d_in[0];
  const float* p_w1  = (const float*)d_in[1];
  const float* p_b1  = (const float*)d_in[2];
  const float* p_dw1 = (const float*)d_in[3];
  const float* p_db1 = (const float*)d_in[4];
  const float* p_g1  = (const float*)d_in[5];
  const float* p_be1 = (const float*)d_in[6];
  const float* p_w2  = (const float*)d_in[7];
  const float* p_b2  = (const float*)d_in[8];
  const float* p_dw2 = (const float*)d_in[9];
  const float* p_db2 = (const float*)d_in[10];
  const float* p_g2  = (const float*)d_in[11];
  const float* p_be2 = (const float*)d_in[12];
  const float* d_w   = (const float*)d_in[13];
  const float* d_b   = (const float*)d_in[14];
  const float* ia_w  = (const float*)d_in[15];
  const float* ia_b  = (const float*)d_in[16];
  const float* ia_g  = (const float*)d_in[17];
  const float* ia_be = (const float*)d_in[18];
  const float* ib_w  = (const float*)d_in[19];
  const float* ib_b  = (const float*)d_in[20];
  const float* ib_g  = (const float*)d_in[21];
  const float* ib_be = (const float*)d_in[22];
  const float* f_g1  = (const float*)d_in[23];
  const float* f_be1 = (const float*)d_in[24];
  const float* f_g2  = (const float*)d_in[25];
  const float* f_be2 = (const float*)d_in[26];
  float* out = (float*)d_out;
  float* ws = (float*)d_ws;

  const size_t SLOT = 37748736ull;  // 8*32*384*384 floats
  float* W0 = ws;
  float* t1 = ws;
  float* t2 = ws + SLOT;
  size_t off = 2 * SLOT;
  float* xm = ws + off;    off += 3538944;
  float* dd1 = ws + off;   off += 4194304;
  float* dd2 = ws + off;   off += 473344;
  float* dd3 = ws + off;   off += 57600;
  float* dd4 = ws + off;   off += 6400;
  float* dd5 = ws + off;   off += 1024;
  float* partA = ws + off; off += 73728;
  float* partB = ws + off; off += 73728;
  float* partP = ws + off; off += 73728;   // prep stats [32][1152][2]
  float* partS = ws + off; off += 8192;    // small stats [C][64][2]
  float* partF = ws + off; off += 147456;  // score stats [64][<=1152][2]
  float* st = ws + off;    off += 512;
  float* W1 = ws + off;
  bool have2 = (ws_size / 4) >= off + 2 * SLOT;

  float* P1SC = st,       *P1SH = st + 32;
  float* P2SC = st + 64,  *P2SH = st + 96;
  float* ASC  = st + 128, *ASH  = st + 160;
  float* BSC  = st + 192, *BSH  = st + 224;
  float* F1SC = st + 256, *F1SH = st + 320;
  float* F2SC = st + 384, *F2SH = st + 448;

  // mode filter + prepare
  mode_kernel<<<dim3(6, 24, 24), 256, 0, stream>>>(x, xm);
  prep_conv1_f<<<1152, 256, 0, stream>>>(xm, p_w1, p_b1, p_dw1, p_db1, t1, partP);
  stats_combine<<<32, 64, 0, stream>>>(partP, 1152, p_g1, p_be1, P1SC, P1SH);
  prep_conv2_f<<<1152, 256, 0, stream>>>(t1, P1SC, P1SH, p_w2, p_b2, p_dw2, p_db2, t2);
  stats_raw<<<32 * 64, 256, 0, stream>>>((const float4*)t2, 32, partS);
  stats_combine<<<32, 64, 0, stream>>>(partS, 64, p_g2, p_be2, P2SC, P2SH);

  dconv<true><<<16384, 256, 0, stream>>>(t2, P2SC, P2SH, d_w, d_b, 384, 128, dd1,
                                         8 * 32 * 128 * 128);

  float* dbuf[5] = {dd1, dd2, dd3, dd4, dd5};
  const int S[5] = {128, 43, 15, 5, 2};
  for (int it = 0; it < 5; ++it) {
    float scl = (float)S[it] / 384.0f;
    upconv_k<0><<<dim3(144, 256), 256, 0, stream>>>(
        dbuf[it], S[it], scl, ia_w, ib_w, ia_b, ib_b,
        nullptr, nullptr, nullptr, nullptr, nullptr, partA, partB, nullptr);
    stats_combine<<<32, 64, 0, stream>>>(partA, 1152, ia_g, ia_be, ASC, ASH);
    stats_combine<<<32, 64, 0, stream>>>(partB, 1152, ib_g, ib_be, BSC, BSH);
    if (it == 0)
      upconv_k<1><<<dim3(144, 256), 256, 0, stream>>>(
          dbuf[it], S[it], scl, ia_w, ib_w, ia_b, ib_b,
          ASC, ASH, BSC, BSH, out, nullptr, nullptr, nullptr);
    else if (it < 4)
      upconv_k<2><<<dim3(144, 256), 256, 0, stream>>>(
          dbuf[it], S[it], scl, ia_w, ib_w, ia_b, ib_b,
          ASC, ASH, BSC, BSH, out, nullptr, nullptr, nullptr);
    else
      upconv_k<3><<<dim3(144, 256), 256, 0, stream>>>(
          dbuf[it], S[it], scl, ia_w, ib_w, ia_b, ib_b,
          ASC, ASH, BSC, BSH, out, nullptr, nullptr, partF);
    if (it < 4) {
      int so = S[it + 1];
      int tot = 8 * 32 * so * so;
      dconv<false><<<(tot + 255) / 256, 256, 0, stream>>>(
          dbuf[it], nullptr, nullptr, d_w, d_b, S[it], so, dbuf[it + 1], tot);
    }
  }

  // ft chain x3 with buffer rotation (race-free halos)
  const float* cur = out;
  for (int k = 0; k < 3; ++k) {
    stats_combine<<<64, 64, 0, stream>>>(partF, (k == 0) ? 1152 : 288, f_g1, f_be1, F1SC, F1SH);
    stats_mlrelu<<<64 * 64, 256, 0, stream>>>((const float4*)cur, F1SC, F1SH, partS);
    stats_combine<<<64, 64, 0, stream>>>(partS, 64, f_g2, f_be2, F2SC, F2SH);
    if (k == 2 && !have2) {
      ft_passH<<<dim3(6, 96, 512), 256, 0, stream>>>(cur, F1SC, F1SH, F2SC, F2SH, W0);
      ft_passV<<<294912, 256, 0, stream>>>(cur, W0, F1SC, F1SH, F2SC, F2SH, 0.2f, out);
    } else {
      float* dst = (k == 0) ? W0 : (k == 1 ? (have2 ? W1 : out) : out);
      ft_fused<<<dim3(36, 512), 256, 0, stream>>>(cur, F1SC, F1SH, F2SC, F2SH, dst,
                                                  (k == 2) ? 0.2f : 1.0f,
                                                  (k < 2) ? partF : nullptr);
      cur = dst;
    }
  }
}

// Round 4
// 2302.460 us; speedup vs baseline: 2.4730x; 1.0705x over previous
//
#include <hip/hip_runtime.h>

#define HW 147456
#define WID 384
#define NB 8
#define NPC 1179648   // per-channel element count = 8*384*384
#define HW4 36864     // HW/4

static __device__ __forceinline__ float lrelu01(float v) { return v >= 0.f ? v : 0.01f * v; }
static __device__ __forceinline__ float mlrelu(float v) { return v > 0.1f ? 0.1f + 0.7f * (v - 0.1f) : v; }

// ---------------------------------------------------------------------------
// Mode pool: quantize x to 17 bins, 11x11 window mode (zero pad -> bin 0),
// first-max tie break. Grid (6,24,24), block 256.
// ---------------------------------------------------------------------------
__global__ __launch_bounds__(256) void mode_kernel(const float* __restrict__ x,
                                                   float* __restrict__ xm) {
  __shared__ unsigned char qt[26 * 76];
  __shared__ unsigned int cc[16 * 5 * 76];
  const int plane = blockIdx.z;
  const int x0 = blockIdx.x * 64;
  const int y0 = blockIdx.y * 16;
  const float* xp = x + (size_t)plane * HW;

  for (int i = threadIdx.x; i < 26 * 76; i += 256) {
    int r = i / 76, ccol = i - r * 76;
    int gy = y0 + r - 5, gx = x0 + ccol - 5;
    unsigned char q = 0;
    if (ccol < 74 && gy >= 0 && gy < WID && gx >= 0 && gx < WID) {
      float v = xp[gy * WID + gx];
      int qi = (int)rintf(v * 15.9375f);
      qi = qi < 0 ? 0 : (qi > 16 ? 16 : qi);
      q = (unsigned char)qi;
    }
    qt[i] = q;
  }
  __syncthreads();

  for (int i = threadIdx.x; i < 16 * 74; i += 256) {
    int yy = i / 74, col = i - yy * 74;
    unsigned int w0 = 0, w1 = 0, w2 = 0, w3 = 0, w4 = 0;
#pragma unroll
    for (int dy = 0; dy < 11; ++dy) {
      int q = qt[(yy + dy) * 76 + col];
      unsigned int inc = 1u << ((q & 3) << 3);
      int wsel = q >> 2;
      w0 += (wsel == 0) ? inc : 0u;
      w1 += (wsel == 1) ? inc : 0u;
      w2 += (wsel == 2) ? inc : 0u;
      w3 += (wsel == 3) ? inc : 0u;
      w4 += (wsel == 4) ? inc : 0u;
    }
    cc[(yy * 5 + 0) * 76 + col] = w0;
    cc[(yy * 5 + 1) * 76 + col] = w1;
    cc[(yy * 5 + 2) * 76 + col] = w2;
    cc[(yy * 5 + 3) * 76 + col] = w3;
    cc[(yy * 5 + 4) * 76 + col] = w4;
  }
  __syncthreads();

  for (int i = threadIdx.x; i < 16 * 64; i += 256) {
    int yy = i / 64, xx = i - yy * 64;
    unsigned int s0 = 0, s1 = 0, s2 = 0, s3 = 0, s4 = 0;
#pragma unroll
    for (int dx = 0; dx < 11; ++dx) {
      int col = xx + dx;
      s0 += cc[(yy * 5 + 0) * 76 + col];
      s1 += cc[(yy * 5 + 1) * 76 + col];
      s2 += cc[(yy * 5 + 2) * 76 + col];
      s3 += cc[(yy * 5 + 3) * 76 + col];
      s4 += cc[(yy * 5 + 4) * 76 + col];
    }
    unsigned int words[5] = {s0, s1, s2, s3, s4};
    int best = 0;
    unsigned int bc = s0 & 0xffu;
#pragma unroll
    for (int bin = 1; bin < 17; ++bin) {
      unsigned int cnt = (words[bin >> 2] >> ((bin & 3) * 8)) & 0xffu;
      if (cnt > bc) { bc = cnt; best = bin; }
    }
    xm[(size_t)plane * HW + (size_t)(y0 + yy) * WID + (x0 + xx)] = best * 0.0625f;
  }
}

// ---------------------------------------------------------------------------
// xm second moments: 3 sums + 6 cross-products, float4. grid 256.
// ---------------------------------------------------------------------------
__global__ __launch_bounds__(256) void xm_mom(const float4* __restrict__ X,
                                              float* __restrict__ part9) {
  float s0 = 0, s1 = 0, s2 = 0, m00 = 0, m01 = 0, m02 = 0, m11 = 0, m12 = 0, m22 = 0;
  const int end = (blockIdx.x + 1) * 1152;
  for (int u = blockIdx.x * 1152 + threadIdx.x; u < end; u += 256) {
    int b = u / HW4, p4 = u - b * HW4;
    const float4* base = X + (size_t)b * 3 * HW4 + p4;
    float4 a = base[0], bb = base[HW4], c = base[2 * HW4];
    s0 += a.x + a.y + a.z + a.w;
    s1 += bb.x + bb.y + bb.z + bb.w;
    s2 += c.x + c.y + c.z + c.w;
    m00 += a.x * a.x + a.y * a.y + a.z * a.z + a.w * a.w;
    m01 += a.x * bb.x + a.y * bb.y + a.z * bb.z + a.w * bb.w;
    m02 += a.x * c.x + a.y * c.y + a.z * c.z + a.w * c.w;
    m11 += bb.x * bb.x + bb.y * bb.y + bb.z * bb.z + bb.w * bb.w;
    m12 += bb.x * c.x + bb.y * c.y + bb.z * c.z + bb.w * c.w;
    m22 += c.x * c.x + c.y * c.y + c.z * c.z + c.w * c.w;
  }
  float vals[9] = {s0, s1, s2, m00, m01, m02, m11, m12, m22};
  int lane = threadIdx.x & 63, wd = threadIdx.x >> 6;
  __shared__ float red[4][9];
#pragma unroll
  for (int j = 0; j < 9; ++j) {
    float v = vals[j];
    for (int off = 32; off; off >>= 1) v += __shfl_down(v, off);
    if (lane == 0) red[wd][j] = v;
  }
  __syncthreads();
  if (threadIdx.x < 9)
    part9[blockIdx.x * 9 + threadIdx.x] =
        red[0][threadIdx.x] + red[1][threadIdx.x] + red[2][threadIdx.x] + red[3][threadIdx.x];
}

// ---------------------------------------------------------------------------
// analytic BN1 affine from xm moments (t1 = sum_c a_c x_c + k is linear)
// ---------------------------------------------------------------------------
__global__ __launch_bounds__(64) void prep1_affine(const float* __restrict__ part9,
                                                   const float* __restrict__ w1,
                                                   const float* __restrict__ b1,
                                                   const float* __restrict__ dw1,
                                                   const float* __restrict__ db1,
                                                   const float* __restrict__ g,
                                                   const float* __restrict__ be,
                                                   float* __restrict__ sc,
                                                   float* __restrict__ sh) {
  __shared__ double M[9];
  if (threadIdx.x < 9) {
    double s = 0.0;
    for (int i = 0; i < 256; ++i) s += (double)part9[i * 9 + threadIdx.x];
    M[threadIdx.x] = s;
  }
  __syncthreads();
  if (threadIdx.x < 32) {
    int o = threadIdx.x;
    double dw = dw1[o];
    double a0 = (double)w1[o * 3] * dw, a1 = (double)w1[o * 3 + 1] * dw,
           a2 = (double)w1[o * 3 + 2] * dw;
    double k = (double)b1[o] * dw + (double)db1[o];
    double N = (double)NPC;
    double lin = (a0 * M[0] + a1 * M[1] + a2 * M[2]) / N;
    double mean = lin + k;
    double e2 = (a0 * a0 * M[3] + a1 * a1 * M[6] + a2 * a2 * M[8] +
                 2.0 * (a0 * a1 * M[4] + a0 * a2 * M[5] + a1 * a2 * M[7])) / N +
                2.0 * k * lin + k * k;
    double var = e2 - mean * mean;
    float rstd = rsqrtf((float)var + 1e-5f);
    float scl = rstd * g[o];
    sc[o] = scl;
    sh[o] = be[o] - (float)mean * scl;
  }
}

// ---------------------------------------------------------------------------
// fused prepare: conv1(3->32)+BN1+lrelu folded, conv2 (32x32) folded with dw2,
// writes t2 + fused raw-stats partials. 2 px/thread, grid 2304.
// ---------------------------------------------------------------------------
__global__ __launch_bounds__(256) void prep_fused(const float* __restrict__ xm,
                                                  const float* __restrict__ w1,
                                                  const float* __restrict__ b1,
                                                  const float* __restrict__ dw1,
                                                  const float* __restrict__ db1,
                                                  const float* __restrict__ P1SC,
                                                  const float* __restrict__ P1SH,
                                                  const float* __restrict__ w2,
                                                  const float* __restrict__ b2,
                                                  const float* __restrict__ dw2,
                                                  const float* __restrict__ db2,
                                                  float* __restrict__ t2,
                                                  float* __restrict__ part) {
  __shared__ float wl[1024];
  __shared__ float c1[32][4];
  __shared__ float bias2[32];
  __shared__ float wred[8][32];
  for (int i = threadIdx.x; i < 1024; i += 256) wl[i] = w2[i] * dw2[i >> 5];
  if (threadIdx.x < 32) {
    int o = threadIdx.x;
    float dw = dw1[o], s1 = P1SC[o];
    c1[o][0] = w1[o * 3] * dw * s1;
    c1[o][1] = w1[o * 3 + 1] * dw * s1;
    c1[o][2] = w1[o * 3 + 2] * dw * s1;
    c1[o][3] = (b1[o] * dw + db1[o]) * s1 + P1SH[o];
    bias2[o] = b2[o] * dw2[o] + db2[o];
  }
  __syncthreads();
  const int p0 = blockIdx.x * 512 + threadIdx.x;
  const int b = p0 / HW, pp = p0 - b * HW;   // 512 | HW, no straddle
  const float* xb = xm + (size_t)b * 3 * HW + pp;
  float h[2][32];
#pragma unroll
  for (int q = 0; q < 2; ++q) {
    float x0 = xb[q * 256], x1 = xb[HW + q * 256], x2 = xb[2 * HW + q * 256];
#pragma unroll
    for (int o = 0; o < 32; ++o) {
      float u = fmaf(x0, c1[o][0], fmaf(x1, c1[o][1], fmaf(x2, c1[o][2], c1[o][3])));
      h[q][o] = lrelu01(u);
    }
  }
  float sv[32], sq[32];
  float* ob = t2 + (size_t)b * 32 * HW + pp;
  const float4* wl4 = reinterpret_cast<const float4*>(wl);
  for (int o = 0; o < 32; ++o) {
    float acc0 = bias2[o], acc1 = bias2[o];
#pragma unroll
    for (int c4 = 0; c4 < 8; ++c4) {
      float4 w4 = wl4[o * 8 + c4];
      int c = c4 * 4;
      acc0 = fmaf(h[0][c], w4.x, acc0);     acc1 = fmaf(h[1][c], w4.x, acc1);
      acc0 = fmaf(h[0][c + 1], w4.y, acc0); acc1 = fmaf(h[1][c + 1], w4.y, acc1);
      acc0 = fmaf(h[0][c + 2], w4.z, acc0); acc1 = fmaf(h[1][c + 2], w4.z, acc1);
      acc0 = fmaf(h[0][c + 3], w4.w, acc0); acc1 = fmaf(h[1][c + 3], w4.w, acc1);
    }
    ob[(size_t)o * HW] = acc0;
    ob[(size_t)o * HW + 256] = acc1;
    sv[o] = acc0 + acc1;
    sq[o] = acc0 * acc0 + acc1 * acc1;
  }
  int lane = threadIdx.x & 63, wd = threadIdx.x >> 6;
#pragma unroll
  for (int o = 0; o < 32; ++o) {
    float a = sv[o], q = sq[o];
    for (int off = 32; off; off >>= 1) {
      a += __shfl_down(a, off);
      q += __shfl_down(q, off);
    }
    if (lane == 0) { wred[wd][o] = a; wred[wd + 4][o] = q; }
  }
  __syncthreads();
  if (threadIdx.x < 32) {
    int o = threadIdx.x;
    part[((size_t)o * 2304 + blockIdx.x) * 2] = wred[0][o] + wred[1][o] + wred[2][o] + wred[3][o];
    part[((size_t)o * 2304 + blockIdx.x) * 2 + 1] = wred[4][o] + wred[5][o] + wred[6][o] + wred[7][o];
  }
}

// ---------------------------------------------------------------------------
// combine partials -> folded affine
// ---------------------------------------------------------------------------
__global__ __launch_bounds__(64) void stats_combine(const float* __restrict__ part, int nsplit,
                                                    const float* __restrict__ g,
                                                    const float* __restrict__ be,
                                                    float* __restrict__ sc,
                                                    float* __restrict__ sh) {
  const int c = blockIdx.x;
  double s = 0.0, q = 0.0;
  for (int i = threadIdx.x; i < nsplit; i += 64) {
    s += part[((size_t)c * nsplit + i) * 2];
    q += part[((size_t)c * nsplit + i) * 2 + 1];
  }
  for (int off = 32; off; off >>= 1) {
    s += __shfl_down(s, off);
    q += __shfl_down(q, off);
  }
  if (threadIdx.x == 0) {
    double mean = s / (double)NPC;
    double var = q / (double)NPC - mean * mean;
    float rstd = rsqrtf((float)var + 1e-5f);
    float scl = rstd * g[c];
    sc[c] = scl;
    sh[c] = be[c] - (float)mean * scl;
  }
}

// ---------------------------------------------------------------------------
// shared depthwise 3x3 stride-3 pad-1 conv; optional bn+lrelu on input
// ---------------------------------------------------------------------------
template <bool AFF>
__global__ __launch_bounds__(256) void dconv(const float* __restrict__ in,
                                             const float* __restrict__ sc,
                                             const float* __restrict__ sh,
                                             const float* __restrict__ w9,
                                             const float* __restrict__ db,
                                             int Sin, int Sout,
                                             float* __restrict__ out, int total) {
  int idx = blockIdx.x * 256 + threadIdx.x;
  if (idx >= total) return;
  int xx = idx % Sout;
  int t = idx / Sout;
  int yy = t % Sout;
  int pc = t / Sout;
  int c = pc & 31;
  const float* ip = in + (size_t)pc * Sin * Sin;
  float a = AFF ? sc[c] : 1.f;
  float h = AFF ? sh[c] : 0.f;
  float acc = 0.f;
#pragma unroll
  for (int ky = 0; ky < 3; ++ky) {
    int iy = 3 * yy - 1 + ky;
    if (iy < 0 || iy >= Sin) continue;
#pragma unroll
    for (int kx = 0; kx < 3; ++kx) {
      int ix = 3 * xx - 1 + kx;
      if (ix < 0 || ix >= Sin) continue;
      float v = ip[(size_t)iy * Sin + ix];
      if (AFF) { v = v * a + h; v = lrelu01(v); }
      acc = fmaf(v, w9[ky * 3 + kx], acc);
    }
  }
  out[idx] = acc + db[0];
}

// ---------------------------------------------------------------------------
// shared helpers for pyramid kernels (zt stride 41, geometry hoisted)
// ---------------------------------------------------------------------------
__device__ __forceinline__ void stage_geo(int Sin, float scale, int tx, int ty,
                                          int* gx0, int* gx1, float* gfx,
                                          int* gy0s, int* gy1s, float* gfy) {
  if (threadIdx.x < 72) {
    int t = threadIdx.x >= 36 ? threadIdx.x - 36 : threadIdx.x;
    bool isY = threadIdx.x >= 36;
    int gp = (isY ? ty : tx) + t - 2;
    int i0, i1;
    float fr;
    if (gp < 0 || gp >= WID) {
      i0 = -1; i1 = 0; fr = 0.f;
    } else {
      float s = (gp + 0.5f) * scale - 0.5f;
      float f0 = floorf(s);
      fr = s - f0;
      int ii = (int)f0;
      i1 = ii + 1 < Sin - 1 ? ii + 1 : Sin - 1;
      i0 = ii > 0 ? ii : 0;
    }
    if (isY) { gy0s[t] = i0; gy1s[t] = i1; gfy[t] = fr; }
    else     { gx0[t] = i0; gx1[t] = i1; gfx[t] = fr; }
  }
}

__device__ __forceinline__ void stage_tile(float* zt, const float* dp, int Sin,
                                           const int* gx0, const int* gx1, const float* gfx,
                                           const int* gy0s, const int* gy1s, const float* gfy) {
  for (int i = threadIdx.x; i < 36 * 36; i += 256) {
    int zy = i / 36, zx = i - zy * 36;
    int iy0 = gy0s[zy], ix0 = gx0[zx];
    float v = 0.f;
    if ((iy0 | ix0) >= 0) {
      int iy1 = gy1s[zy], ix1 = gx1[zx];
      float fx = gfx[zx], fy = gfy[zy];
      float v00 = dp[iy0 * Sin + ix0], v01 = dp[iy0 * Sin + ix1];
      float v10 = dp[iy1 * Sin + ix0], v11 = dp[iy1 * Sin + ix1];
      float top = v00 + fx * (v01 - v00);
      float bot = v10 + fx * (v11 - v10);
      v = top + fy * (bot - top);
    }
    zt[zy * 41 + zx] = v;
  }
}

__device__ __forceinline__ void conv_ab(const float* zt, int row, int g,
                                        const float* wa, const float* wb,
                                        float ba0, float bb0, float* A, float* Bv) {
  float aa0 = ba0, aa1 = ba0, aa2 = ba0, aa3 = ba0;
  float eb0 = bb0, eb1 = bb0, eb2 = bb0, eb3 = bb0;
#pragma unroll
  for (int dy = 0; dy < 5; ++dy) {
    const float* zr = &zt[(row + dy) * 41 + g * 4];
    float z[8];
#pragma unroll
    for (int j = 0; j < 8; ++j) z[j] = zr[j];
#pragma unroll
    for (int dx = 0; dx < 5; ++dx) {
      float wva = wa[dy * 5 + dx], wvb = wb[dy * 5 + dx];
      aa0 = fmaf(z[dx], wva, aa0);
      aa1 = fmaf(z[dx + 1], wva, aa1);
      aa2 = fmaf(z[dx + 2], wva, aa2);
      aa3 = fmaf(z[dx + 3], wva, aa3);
      eb0 = fmaf(z[dx], wvb, eb0);
      eb1 = fmaf(z[dx + 1], wvb, eb1);
      eb2 = fmaf(z[dx + 2], wvb, eb2);
      eb3 = fmaf(z[dx + 3], wvb, eb3);
    }
  }
  A[0] = aa0; A[1] = aa1; A[2] = aa2; A[3] = aa3;
  Bv[0] = eb0; Bv[1] = eb1; Bv[2] = eb2; Bv[3] = eb3;
}

// ---------------------------------------------------------------------------
// pyramid stats for ALL 5 levels (no output writes). grid (144, 256, 5).
// ---------------------------------------------------------------------------
__global__ __launch_bounds__(256) void upstats_all(const float* __restrict__ d1,
                                                   const float* __restrict__ d2,
                                                   const float* __restrict__ d3,
                                                   const float* __restrict__ d4,
                                                   const float* __restrict__ d5,
                                                   const float* __restrict__ wA5,
                                                   const float* __restrict__ wB5,
                                                   const float* __restrict__ bA,
                                                   const float* __restrict__ bB,
                                                   float* __restrict__ partA,
                                                   float* __restrict__ partB) {
  __shared__ float zt[36 * 41];
  __shared__ int gx0[36], gx1[36], gy0s[36], gy1s[36];
  __shared__ float gfx[36], gfy[36];
  __shared__ float red[16];
  const int lvl = blockIdx.z;
  const float* dsel = lvl == 0 ? d1 : lvl == 1 ? d2 : lvl == 2 ? d3 : lvl == 3 ? d4 : d5;
  const int Sin = lvl == 0 ? 128 : lvl == 1 ? 43 : lvl == 2 ? 15 : lvl == 3 ? 5 : 2;
  const float scale = (float)Sin / 384.f;
  const int plane = blockIdx.y, tile = blockIdx.x;
  const int tx = (tile % 12) * 32, ty = (tile / 12) * 32;
  const float* dp = dsel + (size_t)plane * Sin * Sin;

  stage_geo(Sin, scale, tx, ty, gx0, gx1, gfx, gy0s, gy1s, gfy);
  __syncthreads();
  stage_tile(zt, dp, Sin, gx0, gx1, gfx, gy0s, gy1s, gfy);
  float wa[25], wb[25];
#pragma unroll
  for (int k = 0; k < 25; ++k) { wa[k] = wA5[k]; wb[k] = wB5[k]; }
  float ba0 = bA[0], bb0 = bB[0];
  __syncthreads();

  float A[4], Bv[4];
  conv_ab(zt, threadIdx.x >> 3, threadIdx.x & 7, wa, wb, ba0, bb0, A, Bv);
  float sa = A[0] + A[1] + A[2] + A[3];
  float qa = A[0] * A[0] + A[1] * A[1] + A[2] * A[2] + A[3] * A[3];
  float sb = Bv[0] + Bv[1] + Bv[2] + Bv[3];
  float qb = Bv[0] * Bv[0] + Bv[1] * Bv[1] + Bv[2] * Bv[2] + Bv[3] * Bv[3];
  int lane = threadIdx.x & 63, wd = threadIdx.x >> 6;
  for (int off = 32; off; off >>= 1) {
    sa += __shfl_down(sa, off); qa += __shfl_down(qa, off);
    sb += __shfl_down(sb, off); qb += __shfl_down(qb, off);
  }
  if (lane == 0) {
    red[wd * 4] = sa; red[wd * 4 + 1] = qa;
    red[wd * 4 + 2] = sb; red[wd * 4 + 3] = qb;
  }
  __syncthreads();
  if (threadIdx.x == 0) {
    int b = plane >> 5, c = plane & 31;
    size_t pi = (size_t)lvl * 73728 + ((size_t)c * 1152 + (size_t)b * 144 + tile) * 2;
    partA[pi] = red[0] + red[4] + red[8] + red[12];
    partA[pi + 1] = red[1] + red[5] + red[9] + red[13];
    partB[pi] = red[2] + red[6] + red[10] + red[14];
    partB[pi + 1] = red[3] + red[7] + red[11] + red[15];
  }
}

// combine all 10 (level, conv) BN affines. grid (32, 5, 2).
__global__ __launch_bounds__(64) void combine_lvls(const float* __restrict__ partA,
                                                   const float* __restrict__ partB,
                                                   const float* __restrict__ ia_g,
                                                   const float* __restrict__ ia_be,
                                                   const float* __restrict__ ib_g,
                                                   const float* __restrict__ ib_be,
                                                   float* __restrict__ aff) {
  const int c = blockIdx.x, lvl = blockIdx.y, z = blockIdx.z;
  const float* part = (z ? partB : partA) + (size_t)lvl * 73728;
  const float* g = z ? ib_g : ia_g;
  const float* be = z ? ib_be : ia_be;
  double s = 0.0, q = 0.0;
  for (int i = threadIdx.x; i < 1152; i += 64) {
    s += part[((size_t)c * 1152 + i) * 2];
    q += part[((size_t)c * 1152 + i) * 2 + 1];
  }
  for (int off = 32; off; off >>= 1) {
    s += __shfl_down(s, off);
    q += __shfl_down(q, off);
  }
  if (threadIdx.x == 0) {
    double mean = s / (double)NPC;
    double var = q / (double)NPC - mean * mean;
    float rstd = rsqrtf((float)var + 1e-5f);
    float scl = rstd * g[c];
    aff[((z * 5 + lvl) * 2 + 0) * 32 + c] = scl;
    aff[((z * 5 + lvl) * 2 + 1) * 32 + c] = be[c] - (float)mean * scl;
  }
}

// ---------------------------------------------------------------------------
// apply ALL 5 levels: score = sum_lvl lrelu(bn(conv)) for both convs,
// single write + fused raw stats. grid (144, 256).
// ---------------------------------------------------------------------------
__global__ __launch_bounds__(256) void apply_all(const float* __restrict__ d1,
                                                 const float* __restrict__ d2,
                                                 const float* __restrict__ d3,
                                                 const float* __restrict__ d4,
                                                 const float* __restrict__ d5,
                                                 const float* __restrict__ wA5,
                                                 const float* __restrict__ wB5,
                                                 const float* __restrict__ bA,
                                                 const float* __restrict__ bB,
                                                 const float* __restrict__ aff,
                                                 float* __restrict__ outp,
                                                 float* __restrict__ partF) {
  __shared__ float zt[36 * 41];
  __shared__ int gx0[36], gx1[36], gy0s[36], gy1s[36];
  __shared__ float gfx[36], gfy[36];
  __shared__ float red[16];
  const int plane = blockIdx.y, tile = blockIdx.x;
  const int tx = (tile % 12) * 32, ty = (tile / 12) * 32;
  const int b = plane >> 5, c = plane & 31;
  float wa[25], wb[25];
#pragma unroll
  for (int k = 0; k < 25; ++k) { wa[k] = wA5[k]; wb[k] = wB5[k]; }
  const float ba0 = bA[0], bb0 = bB[0];
  const int row = threadIdx.x >> 3, g = threadIdx.x & 7;

  float acA[4] = {0.f, 0.f, 0.f, 0.f}, acB[4] = {0.f, 0.f, 0.f, 0.f};
  for (int lvl = 0; lvl < 5; ++lvl) {
    const float* dsel = lvl == 0 ? d1 : lvl == 1 ? d2 : lvl == 2 ? d3 : lvl == 3 ? d4 : d5;
    const int Sin = lvl == 0 ? 128 : lvl == 1 ? 43 : lvl == 2 ? 15 : lvl == 3 ? 5 : 2;
    const float scale = (float)Sin / 384.f;
    const float* dp = dsel + (size_t)plane * Sin * Sin;
    __syncthreads();
    stage_geo(Sin, scale, tx, ty, gx0, gx1, gfx, gy0s, gy1s, gfy);
    __syncthreads();
    stage_tile(zt, dp, Sin, gx0, gx1, gfx, gy0s, gy1s, gfy);
    __syncthreads();
    float A[4], Bv[4];
    conv_ab(zt, row, g, wa, wb, ba0, bb0, A, Bv);
    float as = aff[(lvl * 2 + 0) * 32 + c], ah = aff[(lvl * 2 + 1) * 32 + c];
    float bs = aff[((5 + lvl) * 2 + 0) * 32 + c], bh = aff[((5 + lvl) * 2 + 1) * 32 + c];
#pragma unroll
    for (int j = 0; j < 4; ++j) {
      acA[j] += lrelu01(fmaf(A[j], as, ah));
      acB[j] += lrelu01(fmaf(Bv[j], bs, bh));
    }
  }
  float4 xa = {acA[0], acA[1], acA[2], acA[3]};
  float4 xb = {acB[0], acB[1], acB[2], acB[3]};
  size_t po = (size_t)(b * 64 + c) * HW + (size_t)(ty + row) * WID + tx + g * 4;
  *reinterpret_cast<float4*>(outp + po) = xa;
  *reinterpret_cast<float4*>(outp + po + (size_t)32 * HW) = xb;

  float sa = xa.x + xa.y + xa.z + xa.w;
  float qa = xa.x * xa.x + xa.y * xa.y + xa.z * xa.z + xa.w * xa.w;
  float sb = xb.x + xb.y + xb.z + xb.w;
  float qb = xb.x * xb.x + xb.y * xb.y + xb.z * xb.z + xb.w * xb.w;
  int lane = threadIdx.x & 63, wd = threadIdx.x >> 6;
  for (int off = 32; off; off >>= 1) {
    sa += __shfl_down(sa, off); qa += __shfl_down(qa, off);
    sb += __shfl_down(sb, off); qb += __shfl_down(qb, off);
  }
  if (lane == 0) {
    red[wd * 4] = sa; red[wd * 4 + 1] = qa;
    red[wd * 4 + 2] = sb; red[wd * 4 + 3] = qb;
  }
  __syncthreads();
  if (threadIdx.x == 0) {
    size_t piA = ((size_t)c * 1152 + (size_t)b * 144 + tile) * 2;
    size_t piB = ((size_t)(c + 32) * 1152 + (size_t)b * 144 + tile) * 2;
    partF[piA] = red[0] + red[4] + red[8] + red[12];
    partF[piA + 1] = red[1] + red[5] + red[9] + red[13];
    partF[piB] = red[2] + red[6] + red[10] + red[14];
    partF[piB + 1] = red[3] + red[7] + red[11] + red[15];
  }
}

// ---------------------------------------------------------------------------
// mlrelu(affine1(x)) stats, C=64, float4. grid = 64*64.
// ---------------------------------------------------------------------------
__global__ __launch_bounds__(256) void stats_mlrelu(const float4* __restrict__ X,
                                                    const float* __restrict__ sc1,
                                                    const float* __restrict__ sh1,
                                                    float* __restrict__ part) {
  int c = blockIdx.x >> 6, s = blockIdx.x & 63;
  float a1 = sc1[c], b1 = sh1[c];
  float sum = 0.f, sq = 0.f;
  int fi = s * 4608 + threadIdx.x;
#pragma unroll 2
  for (int it = 0; it < 18; ++it, fi += 256) {
    int b = fi / HW4, p4 = fi - b * HW4;
    float4 v = X[(size_t)(b * 64 + c) * HW4 + p4];
    float u;
    u = mlrelu(fmaf(v.x, a1, b1)); sum += u; sq += u * u;
    u = mlrelu(fmaf(v.y, a1, b1)); sum += u; sq += u * u;
    u = mlrelu(fmaf(v.z, a1, b1)); sum += u; sq += u * u;
    u = mlrelu(fmaf(v.w, a1, b1)); sum += u; sq += u * u;
  }
  int lane = threadIdx.x & 63, wd = threadIdx.x >> 6;
  for (int off = 32; off; off >>= 1) {
    sum += __shfl_down(sum, off);
    sq += __shfl_down(sq, off);
  }
  __shared__ float red[8];
  if (lane == 0) { red[wd * 2] = sum; red[wd * 2 + 1] = sq; }
  __syncthreads();
  if (threadIdx.x == 0) {
    part[((size_t)c * 64 + s) * 2] = red[0] + red[2] + red[4] + red[6];
    part[((size_t)c * 64 + s) * 2 + 1] = red[1] + red[3] + red[5] + red[7];
  }
}

// ---------------------------------------------------------------------------
// fused ft pass, bank-conflict-free: sl stride 81 (odd -> rows in distinct
// mod-4 bank classes), Hl stride 64 float4. grid (36, 512).
// ---------------------------------------------------------------------------
__global__ __launch_bounds__(256) void ft_fused(const float* __restrict__ src,
                                                const float* __restrict__ F1SC,
                                                const float* __restrict__ F1SH,
                                                const float* __restrict__ F2SC,
                                                const float* __restrict__ F2SH,
                                                float* __restrict__ dst, float fscale,
                                                float* __restrict__ part) {
  __shared__ float sl[74 * 81];
  __shared__ __align__(16) float Hl[74 * 64];
  __shared__ float red[8];
  const int tile = blockIdx.x;
  const int plane = blockIdx.y;
  const int b = plane >> 6, c = plane & 63;
  const int tx = (tile % 6) * 64, ty = (tile / 6) * 64;
  const float a1 = F1SC[c], b1 = F1SH[c], a2 = F2SC[c], b2 = F2SH[c];
  const float* sp = src + (size_t)plane * HW;

  // phase 1: global float4 loads, scalar LDS writes (stride 81)
  for (int i = threadIdx.x; i < 74 * 20; i += 256) {
    int r = i / 20, k = i - r * 20;
    int gy = ty + r - 5, gx = tx + k * 4 - 8;
    float4 sv = {0.f, 0.f, 0.f, 0.f};
    if (gy >= 0 && gy < WID && gx >= 0 && gx < WID) {
      float4 v = *reinterpret_cast<const float4*>(sp + (size_t)gy * WID + gx);
      sv.x = fmaf(mlrelu(fmaf(v.x, a1, b1)), a2, b2);
      sv.y = fmaf(mlrelu(fmaf(v.y, a1, b1)), a2, b2);
      sv.z = fmaf(mlrelu(fmaf(v.z, a1, b1)), a2, b2);
      sv.w = fmaf(mlrelu(fmaf(v.w, a1, b1)), a2, b2);
    }
    int base = r * 81 + k * 4;
    sl[base] = sv.x; sl[base + 1] = sv.y; sl[base + 2] = sv.z; sl[base + 3] = sv.w;
  }
  __syncthreads();

  // phase 2: horizontal sliding 11-sums
  for (int i = threadIdx.x; i < 74 * 16; i += 256) {
    int r = i >> 4, g = i & 15;
    const float* s0 = &sl[r * 81 + g * 4 + 3];
    float v[14];
#pragma unroll
    for (int j = 0; j < 14; ++j) v[j] = s0[j];
    float h0 = v[0] + v[1] + v[2] + v[3] + v[4] + v[5] + v[6] + v[7] + v[8] + v[9] + v[10];
    float h1 = h0 - v[0] + v[11];
    float h2 = h1 - v[1] + v[12];
    float h3 = h2 - v[2] + v[13];
    float4 hh = {h0, h1, h2, h3};
    *reinterpret_cast<float4*>(&Hl[r * 64 + g * 4]) = hh;
  }
  __syncthreads();

  // phase 3: vertical sliding over Hl (float4), center from sl
  const int g = threadIdx.x & 15, ly = threadIdx.x >> 4;
  const int y0 = ly * 4;
  const float4* H4 = reinterpret_cast<const float4*>(Hl);
  float4 acc = H4[y0 * 16 + g];
#pragma unroll
  for (int dy = 1; dy < 11; ++dy) {
    float4 t = H4[(y0 + dy) * 16 + g];
    acc.x += t.x; acc.y += t.y; acc.z += t.z; acc.w += t.w;
  }
  float sum = 0.f, sq = 0.f;
  float* dpo = dst + (size_t)plane * HW;
#pragma unroll
  for (int ry = 0; ry < 4; ++ry) {
    int y = y0 + ry;
    if (ry) {
      float4 ta = H4[(y + 10) * 16 + g];
      float4 tb = H4[(y - 1) * 16 + g];
      acc.x += ta.x - tb.x; acc.y += ta.y - tb.y;
      acc.z += ta.z - tb.z; acc.w += ta.w - tb.w;
    }
    const float* cp = &sl[(y + 5) * 81 + g * 4 + 8];
    float4 o;
    o.x = (2.f * cp[0] - acc.x * (1.f / 121.f)) * fscale;
    o.y = (2.f * cp[1] - acc.y * (1.f / 121.f)) * fscale;
    o.z = (2.f * cp[2] - acc.z * (1.f / 121.f)) * fscale;
    o.w = (2.f * cp[3] - acc.w * (1.f / 121.f)) * fscale;
    *reinterpret_cast<float4*>(dpo + (size_t)(ty + y) * WID + tx + g * 4) = o;
    sum += o.x + o.y + o.z + o.w;
    sq += o.x * o.x + o.y * o.y + o.z * o.z + o.w * o.w;
  }
  if (part) {
    int lane = threadIdx.x & 63, wd = threadIdx.x >> 6;
    for (int off = 32; off; off >>= 1) {
      sum += __shfl_down(sum, off);
      sq += __shfl_down(sq, off);
    }
    if (lane == 0) { red[wd * 2] = sum; red[wd * 2 + 1] = sq; }
    __syncthreads();
    if (threadIdx.x == 0) {
      size_t pi = ((size_t)c * 288 + (size_t)b * 36 + tile) * 2;
      part[pi] = red[0] + red[2] + red[4] + red[6];
      part[pi + 1] = red[1] + red[3] + red[5] + red[7];
    }
  }
}

// ---------------------------------------------------------------------------
extern "C" void kernel_launch(void* const* d_in, const int* in_sizes, int n_in,
                              void* d_out, int out_size, void* d_ws, size_t ws_size,
                              hipStream_t stream) {
  const float* x     = (const float*)d_in[0];
  const float* p_w1  = (const float*)d_in[1];
  const float* p_b1  = (const float*)d_in[2];
  const float* p_dw1 = (const float*)d_in[3];
  const float* p_db1 = (const float*)d_in[4];
  const float* p_g1  = (const float*)d_in[5];
  const float* p_be1 = (const float*)d_in[6];
  const float* p_w2  = (const float*)d_in[7];
  const float* p_b2  = (const float*)d_in[8];
  const float* p_dw2 = (const float*)d_in[9];
  const float* p_db2 = (const float*)d_in[10];
  const float* p_g2  = (const float*)d_in[11];
  const float* p_be2 = (const float*)d_in[12];
  const float* d_w   = (const float*)d_in[13];
  const float* d_b   = (const float*)d_in[14];
  const float* ia_w  = (const float*)d_in[15];
  const float* ia_b  = (const float*)d_in[16];
  const float* ia_g  = (const float*)d_in[17];
  const float* ia_be = (const float*)d_in[18];
  const float* ib_w  = (const float*)d_in[19];
  const float* ib_b  = (const float*)d_in[20];
  const float* ib_g  = (const float*)d_in[21];
  const float* ib_be = (const float*)d_in[22];
  const float* f_g1  = (const float*)d_in[23];
  const float* f_be1 = (const float*)d_in[24];
  const float* f_g2  = (const float*)d_in[25];
  const float* f_be2 = (const float*)d_in[26];
  float* out = (float*)d_out;
  float* ws = (float*)d_ws;

  const size_t SLOT = 37748736ull;  // 8*32*384*384 floats; score = 2*SLOT
  // Big buffers: B0 = ws[0..2SLOT) (ft buf A), B1 = ws[2SLOT..4SLOT) (ft buf B).
  // B0 lower slot doubles as t2 (prep output, dead before ft k0 writes B0).
  // B0 upper slot hosts pyramid-phase partials (dead before ft k0).
  // B1 head hosts xm + dd pyramid (dead before ft k1 writes B1).
  float* B0 = ws;
  float* B1 = ws + 2 * SLOT;
  float* t2 = B0;
  float* partA = B0 + SLOT;                // 368,640  [5][32][1152][2]
  float* partB = partA + 368640;           // 368,640
  float* partP = partB + 368640;           // 147,456  [32][2304][2]
  float* part9 = partP + 147456;           // 2,304    [256][9]
  float* aff   = part9 + 2304;             // 640      [2][5][2][32]
  float* xm  = B1;                         // 3,538,944
  float* dd1 = xm + 3538944;               // 4,194,304
  float* dd2 = dd1 + 4194304;              // 473,344
  float* dd3 = dd2 + 473344;               // 57,600
  float* dd4 = dd3 + 57600;                // 6,400
  float* dd5 = dd4 + 6400;                 // 1,024
  // Persistent (live across ft chain): past 4*SLOT.
  float* partF = ws + 4 * SLOT;            // 147,456  [64][1152][2]
  float* partS = partF + 147456;           // 8,192    [64][64][2]
  float* st    = partS + 8192;             // 512
  // total: 4*SLOT + 156,160 = 151,151,104 floats (< verified ws floor)

  float* P1SC = st,       *P1SH = st + 32;
  float* P2SC = st + 64,  *P2SH = st + 96;
  float* F1SC = st + 128, *F1SH = st + 192;
  float* F2SC = st + 256, *F2SH = st + 320;

  // mode + prepare (t1 never materialized; BN1 affine analytic from xm moments)
  mode_kernel<<<dim3(6, 24, 24), 256, 0, stream>>>(x, xm);
  xm_mom<<<256, 256, 0, stream>>>((const float4*)xm, part9);
  prep1_affine<<<1, 64, 0, stream>>>(part9, p_w1, p_b1, p_dw1, p_db1, p_g1, p_be1, P1SC, P1SH);
  prep_fused<<<2304, 256, 0, stream>>>(xm, p_w1, p_b1, p_dw1, p_db1, P1SC, P1SH,
                                       p_w2, p_b2, p_dw2, p_db2, t2, partP);
  stats_combine<<<32, 64, 0, stream>>>(partP, 2304, p_g2, p_be2, P2SC, P2SH);

  // pyramid d-chain
  dconv<true><<<16384, 256, 0, stream>>>(t2, P2SC, P2SH, d_w, d_b, 384, 128, dd1,
                                         8 * 32 * 128 * 128);
  dconv<false><<<(8 * 32 * 43 * 43 + 255) / 256, 256, 0, stream>>>(
      dd1, nullptr, nullptr, d_w, d_b, 128, 43, dd2, 8 * 32 * 43 * 43);
  dconv<false><<<(8 * 32 * 15 * 15 + 255) / 256, 256, 0, stream>>>(
      dd2, nullptr, nullptr, d_w, d_b, 43, 15, dd3, 8 * 32 * 15 * 15);
  dconv<false><<<(8 * 32 * 5 * 5 + 255) / 256, 256, 0, stream>>>(
      dd3, nullptr, nullptr, d_w, d_b, 15, 5, dd4, 8 * 32 * 5 * 5);
  dconv<false><<<(8 * 32 * 2 * 2 + 255) / 256, 256, 0, stream>>>(
      dd4, nullptr, nullptr, d_w, d_b, 5, 2, dd5, 8 * 32 * 2 * 2);

  // all-level stats, then single-write apply with fused score stats
  upstats_all<<<dim3(144, 256, 5), 256, 0, stream>>>(dd1, dd2, dd3, dd4, dd5,
                                                     ia_w, ib_w, ia_b, ib_b, partA, partB);
  combine_lvls<<<dim3(32, 5, 2), 64, 0, stream>>>(partA, partB, ia_g, ia_be, ib_g, ib_be, aff);
  apply_all<<<dim3(144, 256), 256, 0, stream>>>(dd1, dd2, dd3, dd4, dd5,
                                                ia_w, ib_w, ia_b, ib_b, aff, out, partF);

  // ft chain x3; rotation out -> B0 -> B1 -> out (no aliasing, halo-safe)
  const float* cur = out;
  float* dsts[3] = {B0, B1, out};
  for (int k = 0; k < 3; ++k) {
    stats_combine<<<64, 64, 0, stream>>>(partF, (k == 0) ? 1152 : 288, f_g1, f_be1, F1SC, F1SH);
    stats_mlrelu<<<64 * 64, 256, 0, stream>>>((const float4*)cur, F1SC, F1SH, partS);
    stats_combine<<<64, 64, 0, stream>>>(partS, 64, f_g2, f_be2, F2SC, F2SH);
    ft_fused<<<dim3(36, 512), 256, 0, stream>>>(cur, F1SC, F1SH, F2SC, F2SH, dsts[k],
                                                (k == 2) ? 0.2f : 1.0f,
                                                (k < 2) ? partF : nullptr);
    cur = dsts[k];
  }
}

// Round 5
// 2248.999 us; speedup vs baseline: 2.5318x; 1.0238x over previous
//
#include <hip/hip_runtime.h>

#define HW 147456
#define WID 384
#define NB 8
#define NPC 1179648   // per-channel element count = 8*384*384
#define HW4 36864     // HW/4

static __device__ __forceinline__ float lrelu01(float v) { return v >= 0.f ? v : 0.01f * v; }
static __device__ __forceinline__ float mlrelu(float v) { return v > 0.1f ? 0.1f + 0.7f * (v - 0.1f) : v; }

// ---------------------------------------------------------------------------
// Mode pool: quantize x to 17 bins, 11x11 window mode (zero pad -> bin 0),
// first-max tie break. Grid (6,24,24), block 256.
// ---------------------------------------------------------------------------
__global__ __launch_bounds__(256) void mode_kernel(const float* __restrict__ x,
                                                   float* __restrict__ xm) {
  __shared__ unsigned char qt[26 * 76];
  __shared__ unsigned int cc[16 * 5 * 76];
  const int plane = blockIdx.z;
  const int x0 = blockIdx.x * 64;
  const int y0 = blockIdx.y * 16;
  const float* xp = x + (size_t)plane * HW;

  for (int i = threadIdx.x; i < 26 * 76; i += 256) {
    int r = i / 76, ccol = i - r * 76;
    int gy = y0 + r - 5, gx = x0 + ccol - 5;
    unsigned char q = 0;
    if (ccol < 74 && gy >= 0 && gy < WID && gx >= 0 && gx < WID) {
      float v = xp[gy * WID + gx];
      int qi = (int)rintf(v * 15.9375f);
      qi = qi < 0 ? 0 : (qi > 16 ? 16 : qi);
      q = (unsigned char)qi;
    }
    qt[i] = q;
  }
  __syncthreads();

  for (int i = threadIdx.x; i < 16 * 74; i += 256) {
    int yy = i / 74, col = i - yy * 74;
    unsigned int w0 = 0, w1 = 0, w2 = 0, w3 = 0, w4 = 0;
#pragma unroll
    for (int dy = 0; dy < 11; ++dy) {
      int q = qt[(yy + dy) * 76 + col];
      unsigned int inc = 1u << ((q & 3) << 3);
      int wsel = q >> 2;
      w0 += (wsel == 0) ? inc : 0u;
      w1 += (wsel == 1) ? inc : 0u;
      w2 += (wsel == 2) ? inc : 0u;
      w3 += (wsel == 3) ? inc : 0u;
      w4 += (wsel == 4) ? inc : 0u;
    }
    cc[(yy * 5 + 0) * 76 + col] = w0;
    cc[(yy * 5 + 1) * 76 + col] = w1;
    cc[(yy * 5 + 2) * 76 + col] = w2;
    cc[(yy * 5 + 3) * 76 + col] = w3;
    cc[(yy * 5 + 4) * 76 + col] = w4;
  }
  __syncthreads();

  for (int i = threadIdx.x; i < 16 * 64; i += 256) {
    int yy = i / 64, xx = i - yy * 64;
    unsigned int s0 = 0, s1 = 0, s2 = 0, s3 = 0, s4 = 0;
#pragma unroll
    for (int dx = 0; dx < 11; ++dx) {
      int col = xx + dx;
      s0 += cc[(yy * 5 + 0) * 76 + col];
      s1 += cc[(yy * 5 + 1) * 76 + col];
      s2 += cc[(yy * 5 + 2) * 76 + col];
      s3 += cc[(yy * 5 + 3) * 76 + col];
      s4 += cc[(yy * 5 + 4) * 76 + col];
    }
    unsigned int words[5] = {s0, s1, s2, s3, s4};
    int best = 0;
    unsigned int bc = s0 & 0xffu;
#pragma unroll
    for (int bin = 1; bin < 17; ++bin) {
      unsigned int cnt = (words[bin >> 2] >> ((bin & 3) * 8)) & 0xffu;
      if (cnt > bc) { bc = cnt; best = bin; }
    }
    xm[(size_t)plane * HW + (size_t)(y0 + yy) * WID + (x0 + xx)] = best * 0.0625f;
  }
}

// ---------------------------------------------------------------------------
// xm second moments: 3 sums + 6 cross-products, float4. grid 256.
// ---------------------------------------------------------------------------
__global__ __launch_bounds__(256) void xm_mom(const float4* __restrict__ X,
                                              float* __restrict__ part9) {
  float s0 = 0, s1 = 0, s2 = 0, m00 = 0, m01 = 0, m02 = 0, m11 = 0, m12 = 0, m22 = 0;
  const int end = (blockIdx.x + 1) * 1152;
  for (int u = blockIdx.x * 1152 + threadIdx.x; u < end; u += 256) {
    int b = u / HW4, p4 = u - b * HW4;
    const float4* base = X + (size_t)b * 3 * HW4 + p4;
    float4 a = base[0], bb = base[HW4], c = base[2 * HW4];
    s0 += a.x + a.y + a.z + a.w;
    s1 += bb.x + bb.y + bb.z + bb.w;
    s2 += c.x + c.y + c.z + c.w;
    m00 += a.x * a.x + a.y * a.y + a.z * a.z + a.w * a.w;
    m01 += a.x * bb.x + a.y * bb.y + a.z * bb.z + a.w * bb.w;
    m02 += a.x * c.x + a.y * c.y + a.z * c.z + a.w * c.w;
    m11 += bb.x * bb.x + bb.y * bb.y + bb.z * bb.z + bb.w * bb.w;
    m12 += bb.x * c.x + bb.y * c.y + bb.z * c.z + bb.w * c.w;
    m22 += c.x * c.x + c.y * c.y + c.z * c.z + c.w * c.w;
  }
  float vals[9] = {s0, s1, s2, m00, m01, m02, m11, m12, m22};
  int lane = threadIdx.x & 63, wd = threadIdx.x >> 6;
  __shared__ float red[4][9];
#pragma unroll
  for (int j = 0; j < 9; ++j) {
    float v = vals[j];
    for (int off = 32; off; off >>= 1) v += __shfl_down(v, off);
    if (lane == 0) red[wd][j] = v;
  }
  __syncthreads();
  if (threadIdx.x < 9)
    part9[blockIdx.x * 9 + threadIdx.x] =
        red[0][threadIdx.x] + red[1][threadIdx.x] + red[2][threadIdx.x] + red[3][threadIdx.x];
}

// ---------------------------------------------------------------------------
// analytic BN1 affine from xm moments (t1 = sum_c a_c x_c + k is linear)
// ---------------------------------------------------------------------------
__global__ __launch_bounds__(64) void prep1_affine(const float* __restrict__ part9,
                                                   const float* __restrict__ w1,
                                                   const float* __restrict__ b1,
                                                   const float* __restrict__ dw1,
                                                   const float* __restrict__ db1,
                                                   const float* __restrict__ g,
                                                   const float* __restrict__ be,
                                                   float* __restrict__ sc,
                                                   float* __restrict__ sh) {
  __shared__ double M[9];
  if (threadIdx.x < 9) {
    double s = 0.0;
    for (int i = 0; i < 256; ++i) s += (double)part9[i * 9 + threadIdx.x];
    M[threadIdx.x] = s;
  }
  __syncthreads();
  if (threadIdx.x < 32) {
    int o = threadIdx.x;
    double dw = dw1[o];
    double a0 = (double)w1[o * 3] * dw, a1 = (double)w1[o * 3 + 1] * dw,
           a2 = (double)w1[o * 3 + 2] * dw;
    double k = (double)b1[o] * dw + (double)db1[o];
    double N = (double)NPC;
    double lin = (a0 * M[0] + a1 * M[1] + a2 * M[2]) / N;
    double mean = lin + k;
    double e2 = (a0 * a0 * M[3] + a1 * a1 * M[6] + a2 * a2 * M[8] +
                 2.0 * (a0 * a1 * M[4] + a0 * a2 * M[5] + a1 * a2 * M[7])) / N +
                2.0 * k * lin + k * k;
    double var = e2 - mean * mean;
    float rstd = rsqrtf((float)var + 1e-5f);
    float scl = rstd * g[o];
    sc[o] = scl;
    sh[o] = be[o] - (float)mean * scl;
  }
}

// ---------------------------------------------------------------------------
// fused prepare: conv1(3->32)+BN1+lrelu folded, conv2 (32x32) folded with dw2,
// writes t2 + fused raw-stats partials. 2 px/thread, grid 2304.
// ---------------------------------------------------------------------------
__global__ __launch_bounds__(256) void prep_fused(const float* __restrict__ xm,
                                                  const float* __restrict__ w1,
                                                  const float* __restrict__ b1,
                                                  const float* __restrict__ dw1,
                                                  const float* __restrict__ db1,
                                                  const float* __restrict__ P1SC,
                                                  const float* __restrict__ P1SH,
                                                  const float* __restrict__ w2,
                                                  const float* __restrict__ b2,
                                                  const float* __restrict__ dw2,
                                                  const float* __restrict__ db2,
                                                  float* __restrict__ t2,
                                                  float* __restrict__ part) {
  __shared__ float wl[1024];
  __shared__ float c1[32][4];
  __shared__ float bias2[32];
  __shared__ float wred[8][32];
  for (int i = threadIdx.x; i < 1024; i += 256) wl[i] = w2[i] * dw2[i >> 5];
  if (threadIdx.x < 32) {
    int o = threadIdx.x;
    float dw = dw1[o], s1 = P1SC[o];
    c1[o][0] = w1[o * 3] * dw * s1;
    c1[o][1] = w1[o * 3 + 1] * dw * s1;
    c1[o][2] = w1[o * 3 + 2] * dw * s1;
    c1[o][3] = (b1[o] * dw + db1[o]) * s1 + P1SH[o];
    bias2[o] = b2[o] * dw2[o] + db2[o];
  }
  __syncthreads();
  const int p0 = blockIdx.x * 512 + threadIdx.x;
  const int b = p0 / HW, pp = p0 - b * HW;   // 512 | HW, no straddle
  const float* xb = xm + (size_t)b * 3 * HW + pp;
  float h[2][32];
#pragma unroll
  for (int q = 0; q < 2; ++q) {
    float x0 = xb[q * 256], x1 = xb[HW + q * 256], x2 = xb[2 * HW + q * 256];
#pragma unroll
    for (int o = 0; o < 32; ++o) {
      float u = fmaf(x0, c1[o][0], fmaf(x1, c1[o][1], fmaf(x2, c1[o][2], c1[o][3])));
      h[q][o] = lrelu01(u);
    }
  }
  float sv[32], sq[32];
  float* ob = t2 + (size_t)b * 32 * HW + pp;
  const float4* wl4 = reinterpret_cast<const float4*>(wl);
  for (int o = 0; o < 32; ++o) {
    float acc0 = bias2[o], acc1 = bias2[o];
#pragma unroll
    for (int c4 = 0; c4 < 8; ++c4) {
      float4 w4 = wl4[o * 8 + c4];
      int c = c4 * 4;
      acc0 = fmaf(h[0][c], w4.x, acc0);     acc1 = fmaf(h[1][c], w4.x, acc1);
      acc0 = fmaf(h[0][c + 1], w4.y, acc0); acc1 = fmaf(h[1][c + 1], w4.y, acc1);
      acc0 = fmaf(h[0][c + 2], w4.z, acc0); acc1 = fmaf(h[1][c + 2], w4.z, acc1);
      acc0 = fmaf(h[0][c + 3], w4.w, acc0); acc1 = fmaf(h[1][c + 3], w4.w, acc1);
    }
    ob[(size_t)o * HW] = acc0;
    ob[(size_t)o * HW + 256] = acc1;
    sv[o] = acc0 + acc1;
    sq[o] = acc0 * acc0 + acc1 * acc1;
  }
  int lane = threadIdx.x & 63, wd = threadIdx.x >> 6;
#pragma unroll
  for (int o = 0; o < 32; ++o) {
    float a = sv[o], q = sq[o];
    for (int off = 32; off; off >>= 1) {
      a += __shfl_down(a, off);
      q += __shfl_down(q, off);
    }
    if (lane == 0) { wred[wd][o] = a; wred[wd + 4][o] = q; }
  }
  __syncthreads();
  if (threadIdx.x < 32) {
    int o = threadIdx.x;
    part[((size_t)o * 2304 + blockIdx.x) * 2] = wred[0][o] + wred[1][o] + wred[2][o] + wred[3][o];
    part[((size_t)o * 2304 + blockIdx.x) * 2 + 1] = wred[4][o] + wred[5][o] + wred[6][o] + wred[7][o];
  }
}

// ---------------------------------------------------------------------------
// combine partials -> folded affine
// ---------------------------------------------------------------------------
__global__ __launch_bounds__(64) void stats_combine(const float* __restrict__ part, int nsplit,
                                                    const float* __restrict__ g,
                                                    const float* __restrict__ be,
                                                    float* __restrict__ sc,
                                                    float* __restrict__ sh) {
  const int c = blockIdx.x;
  double s = 0.0, q = 0.0;
  for (int i = threadIdx.x; i < nsplit; i += 64) {
    s += part[((size_t)c * nsplit + i) * 2];
    q += part[((size_t)c * nsplit + i) * 2 + 1];
  }
  for (int off = 32; off; off >>= 1) {
    s += __shfl_down(s, off);
    q += __shfl_down(q, off);
  }
  if (threadIdx.x == 0) {
    double mean = s / (double)NPC;
    double var = q / (double)NPC - mean * mean;
    float rstd = rsqrtf((float)var + 1e-5f);
    float scl = rstd * g[c];
    sc[c] = scl;
    sh[c] = be[c] - (float)mean * scl;
  }
}

// ---------------------------------------------------------------------------
// shared depthwise 3x3 stride-3 pad-1 conv; optional bn+lrelu on input
// ---------------------------------------------------------------------------
template <bool AFF>
__global__ __launch_bounds__(256) void dconv(const float* __restrict__ in,
                                             const float* __restrict__ sc,
                                             const float* __restrict__ sh,
                                             const float* __restrict__ w9,
                                             const float* __restrict__ db,
                                             int Sin, int Sout,
                                             float* __restrict__ out, int total) {
  int idx = blockIdx.x * 256 + threadIdx.x;
  if (idx >= total) return;
  int xx = idx % Sout;
  int t = idx / Sout;
  int yy = t % Sout;
  int pc = t / Sout;
  int c = pc & 31;
  const float* ip = in + (size_t)pc * Sin * Sin;
  float a = AFF ? sc[c] : 1.f;
  float h = AFF ? sh[c] : 0.f;
  float acc = 0.f;
#pragma unroll
  for (int ky = 0; ky < 3; ++ky) {
    int iy = 3 * yy - 1 + ky;
    if (iy < 0 || iy >= Sin) continue;
#pragma unroll
    for (int kx = 0; kx < 3; ++kx) {
      int ix = 3 * xx - 1 + kx;
      if (ix < 0 || ix >= Sin) continue;
      float v = ip[(size_t)iy * Sin + ix];
      if (AFF) { v = v * a + h; v = lrelu01(v); }
      acc = fmaf(v, w9[ky * 3 + kx], acc);
    }
  }
  out[idx] = acc + db[0];
}

// ---------------------------------------------------------------------------
// pyramid helpers: geometry with clamped indices + validity flags (keeps
// row indices monotone), then SEPARABLE staging: x-interp rows into dH once,
// y-interp into zt (bit-exact same lerp math as joint bilinear).
// ---------------------------------------------------------------------------
__device__ __forceinline__ void stage_geo2(int Sin, float scale, int tx, int ty,
                                           int* gx0, int* gx1, float* gfx, float* gxv,
                                           int* gy0, int* gy1, float* gfy, float* gyv) {
  if (threadIdx.x < 72) {
    int t = threadIdx.x >= 36 ? threadIdx.x - 36 : threadIdx.x;
    bool isY = threadIdx.x >= 36;
    int gp = (isY ? ty : tx) + t - 2;
    float valid = (gp >= 0 && gp < WID) ? 1.f : 0.f;
    int gpc = gp < 0 ? 0 : (gp >= WID ? WID - 1 : gp);
    float s = (gpc + 0.5f) * scale - 0.5f;
    float f0 = floorf(s);
    float fr = s - f0;
    int ii = (int)f0;
    int i1 = ii + 1 < Sin - 1 ? ii + 1 : Sin - 1;
    int i0 = ii > 0 ? ii : 0;
    if (isY) { gy0[t] = i0; gy1[t] = i1; gfy[t] = fr; gyv[t] = valid; }
    else     { gx0[t] = i0; gx1[t] = i1; gfx[t] = fr; gxv[t] = valid; }
  }
}

// dH: [nrows][37]; zt: [36][41]. Caller must sync after stage_geo2 and after.
__device__ __forceinline__ void stage_sep(float* zt, float* dH, const float* dp, int Sin,
                                          const int* gx0, const int* gx1,
                                          const float* gfx, const float* gxv,
                                          const int* gy0, const int* gy1,
                                          const float* gfy, const float* gyv,
                                          int rowlo, int nrows) {
  for (int i = threadIdx.x; i < nrows * 36; i += 256) {
    int r = i / 36, zx = i - r * 36;
    const float* drow = dp + (size_t)(rowlo + r) * Sin;
    float v0 = drow[gx0[zx]], v1 = drow[gx1[zx]];
    dH[r * 37 + zx] = (v0 + gfx[zx] * (v1 - v0)) * gxv[zx];
  }
  __syncthreads();
  for (int i = threadIdx.x; i < 36 * 36; i += 256) {
    int zy = i / 36, zx = i - zy * 36;
    float a = dH[(gy0[zy] - rowlo) * 37 + zx];
    float b = dH[(gy1[zy] - rowlo) * 37 + zx];
    zt[zy * 41 + zx] = (a + gfy[zy] * (b - a)) * gyv[zy];
  }
}

__device__ __forceinline__ void conv_ab(const float* zt, int row, int g,
                                        const float* wa, const float* wb,
                                        float ba0, float bb0, float* A, float* Bv) {
  float aa0 = ba0, aa1 = ba0, aa2 = ba0, aa3 = ba0;
  float eb0 = bb0, eb1 = bb0, eb2 = bb0, eb3 = bb0;
#pragma unroll
  for (int dy = 0; dy < 5; ++dy) {
    const float* zr = &zt[(row + dy) * 41 + g * 4];
    float z[8];
#pragma unroll
    for (int j = 0; j < 8; ++j) z[j] = zr[j];
#pragma unroll
    for (int dx = 0; dx < 5; ++dx) {
      float wva = wa[dy * 5 + dx], wvb = wb[dy * 5 + dx];
      aa0 = fmaf(z[dx], wva, aa0);
      aa1 = fmaf(z[dx + 1], wva, aa1);
      aa2 = fmaf(z[dx + 2], wva, aa2);
      aa3 = fmaf(z[dx + 3], wva, aa3);
      eb0 = fmaf(z[dx], wvb, eb0);
      eb1 = fmaf(z[dx + 1], wvb, eb1);
      eb2 = fmaf(z[dx + 2], wvb, eb2);
      eb3 = fmaf(z[dx + 3], wvb, eb3);
    }
  }
  A[0] = aa0; A[1] = aa1; A[2] = aa2; A[3] = aa3;
  Bv[0] = eb0; Bv[1] = eb1; Bv[2] = eb2; Bv[3] = eb3;
}

// ---------------------------------------------------------------------------
// pyramid stats for ALL 5 levels (no output writes). grid (144, 256, 5).
// ---------------------------------------------------------------------------
__global__ __launch_bounds__(256) void upstats_all(const float* __restrict__ d1,
                                                   const float* __restrict__ d2,
                                                   const float* __restrict__ d3,
                                                   const float* __restrict__ d4,
                                                   const float* __restrict__ d5,
                                                   const float* __restrict__ wA5,
                                                   const float* __restrict__ wB5,
                                                   const float* __restrict__ bA,
                                                   const float* __restrict__ bB,
                                                   float* __restrict__ partA,
                                                   float* __restrict__ partB) {
  __shared__ float zt[36 * 41];
  __shared__ float dH[16 * 37];
  __shared__ int gx0[36], gx1[36], gy0[36], gy1[36];
  __shared__ float gfx[36], gfy[36], gxv[36], gyv[36];
  __shared__ float red[16];
  const int lvl = blockIdx.z;
  const float* dsel = lvl == 0 ? d1 : lvl == 1 ? d2 : lvl == 2 ? d3 : lvl == 3 ? d4 : d5;
  const int Sin = lvl == 0 ? 128 : lvl == 1 ? 43 : lvl == 2 ? 15 : lvl == 3 ? 5 : 2;
  const float scale = (float)Sin / 384.f;
  const int plane = blockIdx.y, tile = blockIdx.x;
  const int tx = (tile % 12) * 32, ty = (tile / 12) * 32;
  const float* dp = dsel + (size_t)plane * Sin * Sin;

  stage_geo2(Sin, scale, tx, ty, gx0, gx1, gfx, gxv, gy0, gy1, gfy, gyv);
  float wa[25], wb[25];
#pragma unroll
  for (int k = 0; k < 25; ++k) { wa[k] = wA5[k]; wb[k] = wB5[k]; }
  float ba0 = bA[0], bb0 = bB[0];
  __syncthreads();
  const int rowlo = gy0[0], nrows = gy1[35] - rowlo + 1;
  stage_sep(zt, dH, dp, Sin, gx0, gx1, gfx, gxv, gy0, gy1, gfy, gyv, rowlo, nrows);
  __syncthreads();

  float A[4], Bv[4];
  conv_ab(zt, threadIdx.x >> 3, threadIdx.x & 7, wa, wb, ba0, bb0, A, Bv);
  float sa = A[0] + A[1] + A[2] + A[3];
  float qa = A[0] * A[0] + A[1] * A[1] + A[2] * A[2] + A[3] * A[3];
  float sb = Bv[0] + Bv[1] + Bv[2] + Bv[3];
  float qb = Bv[0] * Bv[0] + Bv[1] * Bv[1] + Bv[2] * Bv[2] + Bv[3] * Bv[3];
  int lane = threadIdx.x & 63, wd = threadIdx.x >> 6;
  for (int off = 32; off; off >>= 1) {
    sa += __shfl_down(sa, off); qa += __shfl_down(qa, off);
    sb += __shfl_down(sb, off); qb += __shfl_down(qb, off);
  }
  if (lane == 0) {
    red[wd * 4] = sa; red[wd * 4 + 1] = qa;
    red[wd * 4 + 2] = sb; red[wd * 4 + 3] = qb;
  }
  __syncthreads();
  if (threadIdx.x == 0) {
    int b = plane >> 5, c = plane & 31;
    size_t pi = (size_t)lvl * 73728 + ((size_t)c * 1152 + (size_t)b * 144 + tile) * 2;
    partA[pi] = red[0] + red[4] + red[8] + red[12];
    partA[pi + 1] = red[1] + red[5] + red[9] + red[13];
    partB[pi] = red[2] + red[6] + red[10] + red[14];
    partB[pi + 1] = red[3] + red[7] + red[11] + red[15];
  }
}

// combine all 10 (level, conv) BN affines. grid (32, 5, 2).
__global__ __launch_bounds__(64) void combine_lvls(const float* __restrict__ partA,
                                                   const float* __restrict__ partB,
                                                   const float* __restrict__ ia_g,
                                                   const float* __restrict__ ia_be,
                                                   const float* __restrict__ ib_g,
                                                   const float* __restrict__ ib_be,
                                                   float* __restrict__ aff) {
  const int c = blockIdx.x, lvl = blockIdx.y, z = blockIdx.z;
  const float* part = (z ? partB : partA) + (size_t)lvl * 73728;
  const float* g = z ? ib_g : ia_g;
  const float* be = z ? ib_be : ia_be;
  double s = 0.0, q = 0.0;
  for (int i = threadIdx.x; i < 1152; i += 64) {
    s += part[((size_t)c * 1152 + i) * 2];
    q += part[((size_t)c * 1152 + i) * 2 + 1];
  }
  for (int off = 32; off; off >>= 1) {
    s += __shfl_down(s, off);
    q += __shfl_down(q, off);
  }
  if (threadIdx.x == 0) {
    double mean = s / (double)NPC;
    double var = q / (double)NPC - mean * mean;
    float rstd = rsqrtf((float)var + 1e-5f);
    float scl = rstd * g[c];
    aff[((z * 5 + lvl) * 2 + 0) * 32 + c] = scl;
    aff[((z * 5 + lvl) * 2 + 1) * 32 + c] = be[c] - (float)mean * scl;
  }
}

// ---------------------------------------------------------------------------
// apply ALL 5 levels: score = sum_lvl lrelu(bn(conv)) for both convs,
// single write + fused raw stats. grid (144, 256).
// ---------------------------------------------------------------------------
__global__ __launch_bounds__(256) void apply_all(const float* __restrict__ d1,
                                                 const float* __restrict__ d2,
                                                 const float* __restrict__ d3,
                                                 const float* __restrict__ d4,
                                                 const float* __restrict__ d5,
                                                 const float* __restrict__ wA5,
                                                 const float* __restrict__ wB5,
                                                 const float* __restrict__ bA,
                                                 const float* __restrict__ bB,
                                                 const float* __restrict__ aff,
                                                 float* __restrict__ outp,
                                                 float* __restrict__ partF) {
  __shared__ float zt[36 * 41];
  __shared__ float dH[16 * 37];
  __shared__ int gx0[36], gx1[36], gy0[36], gy1[36];
  __shared__ float gfx[36], gfy[36], gxv[36], gyv[36];
  __shared__ float red[16];
  const int plane = blockIdx.y, tile = blockIdx.x;
  const int tx = (tile % 12) * 32, ty = (tile / 12) * 32;
  const int b = plane >> 5, c = plane & 31;
  float wa[25], wb[25];
#pragma unroll
  for (int k = 0; k < 25; ++k) { wa[k] = wA5[k]; wb[k] = wB5[k]; }
  const float ba0 = bA[0], bb0 = bB[0];
  const int row = threadIdx.x >> 3, g = threadIdx.x & 7;

  float acA[4] = {0.f, 0.f, 0.f, 0.f}, acB[4] = {0.f, 0.f, 0.f, 0.f};
  for (int lvl = 0; lvl < 5; ++lvl) {
    const float* dsel = lvl == 0 ? d1 : lvl == 1 ? d2 : lvl == 2 ? d3 : lvl == 3 ? d4 : d5;
    const int Sin = lvl == 0 ? 128 : lvl == 1 ? 43 : lvl == 2 ? 15 : lvl == 3 ? 5 : 2;
    const float scale = (float)Sin / 384.f;
    const float* dp = dsel + (size_t)plane * Sin * Sin;
    __syncthreads();   // protect zt/dH/geo from previous iteration's readers
    stage_geo2(Sin, scale, tx, ty, gx0, gx1, gfx, gxv, gy0, gy1, gfy, gyv);
    __syncthreads();
    const int rowlo = gy0[0], nrows = gy1[35] - rowlo + 1;
    stage_sep(zt, dH, dp, Sin, gx0, gx1, gfx, gxv, gy0, gy1, gfy, gyv, rowlo, nrows);
    __syncthreads();
    float A[4], Bv[4];
    conv_ab(zt, row, g, wa, wb, ba0, bb0, A, Bv);
    float as = aff[(lvl * 2 + 0) * 32 + c], ah = aff[(lvl * 2 + 1) * 32 + c];
    float bs = aff[((5 + lvl) * 2 + 0) * 32 + c], bh = aff[((5 + lvl) * 2 + 1) * 32 + c];
#pragma unroll
    for (int j = 0; j < 4; ++j) {
      acA[j] += lrelu01(fmaf(A[j], as, ah));
      acB[j] += lrelu01(fmaf(Bv[j], bs, bh));
    }
  }
  float4 xa = {acA[0], acA[1], acA[2], acA[3]};
  float4 xb = {acB[0], acB[1], acB[2], acB[3]};
  size_t po = (size_t)(b * 64 + c) * HW + (size_t)(ty + row) * WID + tx + g * 4;
  *reinterpret_cast<float4*>(outp + po) = xa;
  *reinterpret_cast<float4*>(outp + po + (size_t)32 * HW) = xb;

  float sa = xa.x + xa.y + xa.z + xa.w;
  float qa = xa.x * xa.x + xa.y * xa.y + xa.z * xa.z + xa.w * xa.w;
  float sb = xb.x + xb.y + xb.z + xb.w;
  float qb = xb.x * xb.x + xb.y * xb.y + xb.z * xb.z + xb.w * xb.w;
  int lane = threadIdx.x & 63, wd = threadIdx.x >> 6;
  for (int off = 32; off; off >>= 1) {
    sa += __shfl_down(sa, off); qa += __shfl_down(qa, off);
    sb += __shfl_down(sb, off); qb += __shfl_down(qb, off);
  }
  if (lane == 0) {
    red[wd * 4] = sa; red[wd * 4 + 1] = qa;
    red[wd * 4 + 2] = sb; red[wd * 4 + 3] = qb;
  }
  __syncthreads();
  if (threadIdx.x == 0) {
    size_t piA = ((size_t)c * 1152 + (size_t)b * 144 + tile) * 2;
    size_t piB = ((size_t)(c + 32) * 1152 + (size_t)b * 144 + tile) * 2;
    partF[piA] = red[0] + red[4] + red[8] + red[12];
    partF[piA + 1] = red[1] + red[5] + red[9] + red[13];
    partF[piB] = red[2] + red[6] + red[10] + red[14];
    partF[piB + 1] = red[3] + red[7] + red[11] + red[15];
  }
}

// ---------------------------------------------------------------------------
// mlrelu(affine1(x)) stats, C=64, float4. grid = 64*64.
// ---------------------------------------------------------------------------
__global__ __launch_bounds__(256) void stats_mlrelu(const float4* __restrict__ X,
                                                    const float* __restrict__ sc1,
                                                    const float* __restrict__ sh1,
                                                    float* __restrict__ part) {
  int c = blockIdx.x >> 6, s = blockIdx.x & 63;
  float a1 = sc1[c], b1 = sh1[c];
  float sum = 0.f, sq = 0.f;
  int fi = s * 4608 + threadIdx.x;
#pragma unroll 2
  for (int it = 0; it < 18; ++it, fi += 256) {
    int b = fi / HW4, p4 = fi - b * HW4;
    float4 v = X[(size_t)(b * 64 + c) * HW4 + p4];
    float u;
    u = mlrelu(fmaf(v.x, a1, b1)); sum += u; sq += u * u;
    u = mlrelu(fmaf(v.y, a1, b1)); sum += u; sq += u * u;
    u = mlrelu(fmaf(v.z, a1, b1)); sum += u; sq += u * u;
    u = mlrelu(fmaf(v.w, a1, b1)); sum += u; sq += u * u;
  }
  int lane = threadIdx.x & 63, wd = threadIdx.x >> 6;
  for (int off = 32; off; off >>= 1) {
    sum += __shfl_down(sum, off);
    sq += __shfl_down(sq, off);
  }
  __shared__ float red[8];
  if (lane == 0) { red[wd * 2] = sum; red[wd * 2 + 1] = sq; }
  __syncthreads();
  if (threadIdx.x == 0) {
    part[((size_t)c * 64 + s) * 2] = red[0] + red[2] + red[4] + red[6];
    part[((size_t)c * 64 + s) * 2 + 1] = red[1] + red[3] + red[5] + red[7];
  }
}

// ---------------------------------------------------------------------------
// fused ft pass, bank-conflict-free: sl stride 81, Hl stride 64 float4.
// grid (36, 512).
// ---------------------------------------------------------------------------
__global__ __launch_bounds__(256) void ft_fused(const float* __restrict__ src,
                                                const float* __restrict__ F1SC,
                                                const float* __restrict__ F1SH,
                                                const float* __restrict__ F2SC,
                                                const float* __restrict__ F2SH,
                                                float* __restrict__ dst, float fscale,
                                                float* __restrict__ part) {
  __shared__ float sl[74 * 81];
  __shared__ __align__(16) float Hl[74 * 64];
  __shared__ float red[8];
  const int tile = blockIdx.x;
  const int plane = blockIdx.y;
  const int b = plane >> 6, c = plane & 63;
  const int tx = (tile % 6) * 64, ty = (tile / 6) * 64;
  const float a1 = F1SC[c], b1 = F1SH[c], a2 = F2SC[c], b2 = F2SH[c];
  const float* sp = src + (size_t)plane * HW;

  for (int i = threadIdx.x; i < 74 * 20; i += 256) {
    int r = i / 20, k = i - r * 20;
    int gy = ty + r - 5, gx = tx + k * 4 - 8;
    float4 sv = {0.f, 0.f, 0.f, 0.f};
    if (gy >= 0 && gy < WID && gx >= 0 && gx < WID) {
      float4 v = *reinterpret_cast<const float4*>(sp + (size_t)gy * WID + gx);
      sv.x = fmaf(mlrelu(fmaf(v.x, a1, b1)), a2, b2);
      sv.y = fmaf(mlrelu(fmaf(v.y, a1, b1)), a2, b2);
      sv.z = fmaf(mlrelu(fmaf(v.z, a1, b1)), a2, b2);
      sv.w = fmaf(mlrelu(fmaf(v.w, a1, b1)), a2, b2);
    }
    int base = r * 81 + k * 4;
    sl[base] = sv.x; sl[base + 1] = sv.y; sl[base + 2] = sv.z; sl[base + 3] = sv.w;
  }
  __syncthreads();

  for (int i = threadIdx.x; i < 74 * 16; i += 256) {
    int r = i >> 4, g = i & 15;
    const float* s0 = &sl[r * 81 + g * 4 + 3];
    float v[14];
#pragma unroll
    for (int j = 0; j < 14; ++j) v[j] = s0[j];
    float h0 = v[0] + v[1] + v[2] + v[3] + v[4] + v[5] + v[6] + v[7] + v[8] + v[9] + v[10];
    float h1 = h0 - v[0] + v[11];
    float h2 = h1 - v[1] + v[12];
    float h3 = h2 - v[2] + v[13];
    float4 hh = {h0, h1, h2, h3};
    *reinterpret_cast<float4*>(&Hl[r * 64 + g * 4]) = hh;
  }
  __syncthreads();

  const int g = threadIdx.x & 15, ly = threadIdx.x >> 4;
  const int y0 = ly * 4;
  const float4* H4 = reinterpret_cast<const float4*>(Hl);
  float4 acc = H4[y0 * 16 + g];
#pragma unroll
  for (int dy = 1; dy < 11; ++dy) {
    float4 t = H4[(y0 + dy) * 16 + g];
    acc.x += t.x; acc.y += t.y; acc.z += t.z; acc.w += t.w;
  }
  float sum = 0.f, sq = 0.f;
  float* dpo = dst + (size_t)plane * HW;
#pragma unroll
  for (int ry = 0; ry < 4; ++ry) {
    int y = y0 + ry;
    if (ry) {
      float4 ta = H4[(y + 10) * 16 + g];
      float4 tb = H4[(y - 1) * 16 + g];
      acc.x += ta.x - tb.x; acc.y += ta.y - tb.y;
      acc.z += ta.z - tb.z; acc.w += ta.w - tb.w;
    }
    const float* cp = &sl[(y + 5) * 81 + g * 4 + 8];
    float4 o;
    o.x = (2.f * cp[0] - acc.x * (1.f / 121.f)) * fscale;
    o.y = (2.f * cp[1] - acc.y * (1.f / 121.f)) * fscale;
    o.z = (2.f * cp[2] - acc.z * (1.f / 121.f)) * fscale;
    o.w = (2.f * cp[3] - acc.w * (1.f / 121.f)) * fscale;
    *reinterpret_cast<float4*>(dpo + (size_t)(ty + y) * WID + tx + g * 4) = o;
    sum += o.x + o.y + o.z + o.w;
    sq += o.x * o.x + o.y * o.y + o.z * o.z + o.w * o.w;
  }
  if (part) {
    int lane = threadIdx.x & 63, wd = threadIdx.x >> 6;
    for (int off = 32; off; off >>= 1) {
      sum += __shfl_down(sum, off);
      sq += __shfl_down(sq, off);
    }
    if (lane == 0) { red[wd * 2] = sum; red[wd * 2 + 1] = sq; }
    __syncthreads();
    if (threadIdx.x == 0) {
      size_t pi = ((size_t)c * 288 + (size_t)b * 36 + tile) * 2;
      part[pi] = red[0] + red[2] + red[4] + red[6];
      part[pi + 1] = red[1] + red[3] + red[5] + red[7];
    }
  }
}

// ---------------------------------------------------------------------------
extern "C" void kernel_launch(void* const* d_in, const int* in_sizes, int n_in,
                              void* d_out, int out_size, void* d_ws, size_t ws_size,
                              hipStream_t stream) {
  const float* x     = (const float*)d_in[0];
  const float* p_w1  = (const float*)d_in[1];
  const float* p_b1  = (const float*)d_in[2];
  const float* p_dw1 = (const float*)d_in[3];
  const float* p_db1 = (const float*)d_in[4];
  const float* p_g1  = (const float*)d_in[5];
  const float* p_be1 = (const float*)d_in[6];
  const float* p_w2  = (const float*)d_in[7];
  const float* p_b2  = (const float*)d_in[8];
  const float* p_dw2 = (const float*)d_in[9];
  const float* p_db2 = (const float*)d_in[10];
  const float* p_g2  = (const float*)d_in[11];
  const float* p_be2 = (const float*)d_in[12];
  const float* d_w   = (const float*)d_in[13];
  const float* d_b   = (const float*)d_in[14];
  const float* ia_w  = (const float*)d_in[15];
  const float* ia_b  = (const float*)d_in[16];
  const float* ia_g  = (const float*)d_in[17];
  const float* ia_be = (const float*)d_in[18];
  const float* ib_w  = (const float*)d_in[19];
  const float* ib_b  = (const float*)d_in[20];
  const float* ib_g  = (const float*)d_in[21];
  const float* ib_be = (const float*)d_in[22];
  const float* f_g1  = (const float*)d_in[23];
  const float* f_be1 = (const float*)d_in[24];
  const float* f_g2  = (const float*)d_in[25];
  const float* f_be2 = (const float*)d_in[26];
  float* out = (float*)d_out;
  float* ws = (float*)d_ws;

  const size_t SLOT = 37748736ull;  // 8*32*384*384 floats; score = 2*SLOT
  float* B0 = ws;
  float* B1 = ws + 2 * SLOT;
  float* t2 = B0;
  float* partA = B0 + SLOT;                // 368,640  [5][32][1152][2]
  float* partB = partA + 368640;           // 368,640
  float* partP = partB + 368640;           // 147,456  [32][2304][2]
  float* part9 = partP + 147456;           // 2,304    [256][9]
  float* aff   = part9 + 2304;             // 640      [2][5][2][32]
  float* xm  = B1;                         // 3,538,944
  float* dd1 = xm + 3538944;               // 4,194,304
  float* dd2 = dd1 + 4194304;              // 473,344
  float* dd3 = dd2 + 473344;               // 57,600
  float* dd4 = dd3 + 57600;                // 6,400
  float* dd5 = dd4 + 6400;                 // 1,024
  float* partF = ws + 4 * SLOT;            // 147,456  [64][1152][2]
  float* partS = partF + 147456;           // 8,192    [64][64][2]
  float* st    = partS + 8192;             // 512

  float* P1SC = st,       *P1SH = st + 32;
  float* P2SC = st + 64,  *P2SH = st + 96;
  float* F1SC = st + 128, *F1SH = st + 192;
  float* F2SC = st + 256, *F2SH = st + 320;

  // mode + prepare (t1 never materialized; BN1 affine analytic from xm moments)
  mode_kernel<<<dim3(6, 24, 24), 256, 0, stream>>>(x, xm);
  xm_mom<<<256, 256, 0, stream>>>((const float4*)xm, part9);
  prep1_affine<<<1, 64, 0, stream>>>(part9, p_w1, p_b1, p_dw1, p_db1, p_g1, p_be1, P1SC, P1SH);
  prep_fused<<<2304, 256, 0, stream>>>(xm, p_w1, p_b1, p_dw1, p_db1, P1SC, P1SH,
                                       p_w2, p_b2, p_dw2, p_db2, t2, partP);
  stats_combine<<<32, 64, 0, stream>>>(partP, 2304, p_g2, p_be2, P2SC, P2SH);

  // pyramid d-chain
  dconv<true><<<16384, 256, 0, stream>>>(t2, P2SC, P2SH, d_w, d_b, 384, 128, dd1,
                                         8 * 32 * 128 * 128);
  dconv<false><<<(8 * 32 * 43 * 43 + 255) / 256, 256, 0, stream>>>(
      dd1, nullptr, nullptr, d_w, d_b, 128, 43, dd2, 8 * 32 * 43 * 43);
  dconv<false><<<(8 * 32 * 15 * 15 + 255) / 256, 256, 0, stream>>>(
      dd2, nullptr, nullptr, d_w, d_b, 43, 15, dd3, 8 * 32 * 15 * 15);
  dconv<false><<<(8 * 32 * 5 * 5 + 255) / 256, 256, 0, stream>>>(
      dd3, nullptr, nullptr, d_w, d_b, 15, 5, dd4, 8 * 32 * 5 * 5);
  dconv<false><<<(8 * 32 * 2 * 2 + 255) / 256, 256, 0, stream>>>(
      dd4, nullptr, nullptr, d_w, d_b, 5, 2, dd5, 8 * 32 * 2 * 2);

  // all-level stats, then single-write apply with fused score stats
  upstats_all<<<dim3(144, 256, 5), 256, 0, stream>>>(dd1, dd2, dd3, dd4, dd5,
                                                     ia_w, ib_w, ia_b, ib_b, partA, partB);
  combine_lvls<<<dim3(32, 5, 2), 64, 0, stream>>>(partA, partB, ia_g, ia_be, ib_g, ib_be, aff);
  apply_all<<<dim3(144, 256), 256, 0, stream>>>(dd1, dd2, dd3, dd4, dd5,
                                                ia_w, ib_w, ia_b, ib_b, aff, out, partF);

  // ft chain x3; rotation out -> B0 -> B1 -> out (no aliasing, halo-safe)
  const float* cur = out;
  float* dsts[3] = {B0, B1, out};
  for (int k = 0; k < 3; ++k) {
    stats_combine<<<64, 64, 0, stream>>>(partF, (k == 0) ? 1152 : 288, f_g1, f_be1, F1SC, F1SH);
    stats_mlrelu<<<64 * 64, 256, 0, stream>>>((const float4*)cur, F1SC, F1SH, partS);
    stats_combine<<<64, 64, 0, stream>>>(partS, 64, f_g2, f_be2, F2SC, F2SH);
    ft_fused<<<dim3(36, 512), 256, 0, stream>>>(cur, F1SC, F1SH, F2SC, F2SH, dsts[k],
                                                (k == 2) ? 0.2f : 1.0f,
                                                (k < 2) ? partF : nullptr);
    cur = dsts[k];
  }
}

// Round 6
// 2131.245 us; speedup vs baseline: 2.6717x; 1.0553x over previous
//
#include <hip/hip_runtime.h>

#define HW 147456
#define WID 384
#define NB 8
#define NPC 1179648   // per-channel element count = 8*384*384
#define HW4 36864     // HW/4

static __device__ __forceinline__ float lrelu01(float v) { return v >= 0.f ? v : 0.01f * v; }
static __device__ __forceinline__ float mlrelu(float v) { return v > 0.1f ? 0.1f + 0.7f * (v - 0.1f) : v; }

// ---------------------------------------------------------------------------
// Mode pool: quantize x to 17 bins, 11x11 window mode (zero pad -> bin 0),
// first-max tie break. Grid (6,24,24), block 256.
// ---------------------------------------------------------------------------
__global__ __launch_bounds__(256) void mode_kernel(const float* __restrict__ x,
                                                   float* __restrict__ xm) {
  __shared__ unsigned char qt[26 * 76];
  __shared__ unsigned int cc[16 * 5 * 76];
  const int plane = blockIdx.z;
  const int x0 = blockIdx.x * 64;
  const int y0 = blockIdx.y * 16;
  const float* xp = x + (size_t)plane * HW;

  for (int i = threadIdx.x; i < 26 * 76; i += 256) {
    int r = i / 76, ccol = i - r * 76;
    int gy = y0 + r - 5, gx = x0 + ccol - 5;
    unsigned char q = 0;
    if (ccol < 74 && gy >= 0 && gy < WID && gx >= 0 && gx < WID) {
      float v = xp[gy * WID + gx];
      int qi = (int)rintf(v * 15.9375f);
      qi = qi < 0 ? 0 : (qi > 16 ? 16 : qi);
      q = (unsigned char)qi;
    }
    qt[i] = q;
  }
  __syncthreads();

  for (int i = threadIdx.x; i < 16 * 74; i += 256) {
    int yy = i / 74, col = i - yy * 74;
    unsigned int w0 = 0, w1 = 0, w2 = 0, w3 = 0, w4 = 0;
#pragma unroll
    for (int dy = 0; dy < 11; ++dy) {
      int q = qt[(yy + dy) * 76 + col];
      unsigned int inc = 1u << ((q & 3) << 3);
      int wsel = q >> 2;
      w0 += (wsel == 0) ? inc : 0u;
      w1 += (wsel == 1) ? inc : 0u;
      w2 += (wsel == 2) ? inc : 0u;
      w3 += (wsel == 3) ? inc : 0u;
      w4 += (wsel == 4) ? inc : 0u;
    }
    cc[(yy * 5 + 0) * 76 + col] = w0;
    cc[(yy * 5 + 1) * 76 + col] = w1;
    cc[(yy * 5 + 2) * 76 + col] = w2;
    cc[(yy * 5 + 3) * 76 + col] = w3;
    cc[(yy * 5 + 4) * 76 + col] = w4;
  }
  __syncthreads();

  for (int i = threadIdx.x; i < 16 * 64; i += 256) {
    int yy = i / 64, xx = i - yy * 64;
    unsigned int s0 = 0, s1 = 0, s2 = 0, s3 = 0, s4 = 0;
#pragma unroll
    for (int dx = 0; dx < 11; ++dx) {
      int col = xx + dx;
      s0 += cc[(yy * 5 + 0) * 76 + col];
      s1 += cc[(yy * 5 + 1) * 76 + col];
      s2 += cc[(yy * 5 + 2) * 76 + col];
      s3 += cc[(yy * 5 + 3) * 76 + col];
      s4 += cc[(yy * 5 + 4) * 76 + col];
    }
    unsigned int words[5] = {s0, s1, s2, s3, s4};
    int best = 0;
    unsigned int bc = s0 & 0xffu;
#pragma unroll
    for (int bin = 1; bin < 17; ++bin) {
      unsigned int cnt = (words[bin >> 2] >> ((bin & 3) * 8)) & 0xffu;
      if (cnt > bc) { bc = cnt; best = bin; }
    }
    xm[(size_t)plane * HW + (size_t)(y0 + yy) * WID + (x0 + xx)] = best * 0.0625f;
  }
}

// ---------------------------------------------------------------------------
// xm second moments: 3 sums + 6 cross-products, float4. grid 256.
// ---------------------------------------------------------------------------
__global__ __launch_bounds__(256) void xm_mom(const float4* __restrict__ X,
                                              float* __restrict__ part9) {
  float s0 = 0, s1 = 0, s2 = 0, m00 = 0, m01 = 0, m02 = 0, m11 = 0, m12 = 0, m22 = 0;
  const int end = (blockIdx.x + 1) * 1152;
  for (int u = blockIdx.x * 1152 + threadIdx.x; u < end; u += 256) {
    int b = u / HW4, p4 = u - b * HW4;
    const float4* base = X + (size_t)b * 3 * HW4 + p4;
    float4 a = base[0], bb = base[HW4], c = base[2 * HW4];
    s0 += a.x + a.y + a.z + a.w;
    s1 += bb.x + bb.y + bb.z + bb.w;
    s2 += c.x + c.y + c.z + c.w;
    m00 += a.x * a.x + a.y * a.y + a.z * a.z + a.w * a.w;
    m01 += a.x * bb.x + a.y * bb.y + a.z * bb.z + a.w * bb.w;
    m02 += a.x * c.x + a.y * c.y + a.z * c.z + a.w * c.w;
    m11 += bb.x * bb.x + bb.y * bb.y + bb.z * bb.z + bb.w * bb.w;
    m12 += bb.x * c.x + bb.y * c.y + bb.z * c.z + bb.w * c.w;
    m22 += c.x * c.x + c.y * c.y + c.z * c.z + c.w * c.w;
  }
  float vals[9] = {s0, s1, s2, m00, m01, m02, m11, m12, m22};
  int lane = threadIdx.x & 63, wd = threadIdx.x >> 6;
  __shared__ float red[4][9];
#pragma unroll
  for (int j = 0; j < 9; ++j) {
    float v = vals[j];
    for (int off = 32; off; off >>= 1) v += __shfl_down(v, off);
    if (lane == 0) red[wd][j] = v;
  }
  __syncthreads();
  if (threadIdx.x < 9)
    part9[blockIdx.x * 9 + threadIdx.x] =
        red[0][threadIdx.x] + red[1][threadIdx.x] + red[2][threadIdx.x] + red[3][threadIdx.x];
}

// ---------------------------------------------------------------------------
// analytic BN1 affine from xm moments (t1 = sum_c a_c x_c + k is linear)
// ---------------------------------------------------------------------------
__global__ __launch_bounds__(64) void prep1_affine(const float* __restrict__ part9,
                                                   const float* __restrict__ w1,
                                                   const float* __restrict__ b1,
                                                   const float* __restrict__ dw1,
                                                   const float* __restrict__ db1,
                                                   const float* __restrict__ g,
                                                   const float* __restrict__ be,
                                                   float* __restrict__ sc,
                                                   float* __restrict__ sh) {
  __shared__ double M[9];
  if (threadIdx.x < 9) {
    double s = 0.0;
    for (int i = 0; i < 256; ++i) s += (double)part9[i * 9 + threadIdx.x];
    M[threadIdx.x] = s;
  }
  __syncthreads();
  if (threadIdx.x < 32) {
    int o = threadIdx.x;
    double dw = dw1[o];
    double a0 = (double)w1[o * 3] * dw, a1 = (double)w1[o * 3 + 1] * dw,
           a2 = (double)w1[o * 3 + 2] * dw;
    double k = (double)b1[o] * dw + (double)db1[o];
    double N = (double)NPC;
    double lin = (a0 * M[0] + a1 * M[1] + a2 * M[2]) / N;
    double mean = lin + k;
    double e2 = (a0 * a0 * M[3] + a1 * a1 * M[6] + a2 * a2 * M[8] +
                 2.0 * (a0 * a1 * M[4] + a0 * a2 * M[5] + a1 * a2 * M[7])) / N +
                2.0 * k * lin + k * k;
    double var = e2 - mean * mean;
    float rstd = rsqrtf((float)var + 1e-5f);
    float scl = rstd * g[o];
    sc[o] = scl;
    sh[o] = be[o] - (float)mean * scl;
  }
}

// ---------------------------------------------------------------------------
// fused prepare: conv1(3->32)+BN1+lrelu folded, conv2 (32x32) folded with dw2,
// writes t2 + fused raw-stats partials. 2 px/thread, grid 2304.
// ---------------------------------------------------------------------------
__global__ __launch_bounds__(256) void prep_fused(const float* __restrict__ xm,
                                                  const float* __restrict__ w1,
                                                  const float* __restrict__ b1,
                                                  const float* __restrict__ dw1,
                                                  const float* __restrict__ db1,
                                                  const float* __restrict__ P1SC,
                                                  const float* __restrict__ P1SH,
                                                  const float* __restrict__ w2,
                                                  const float* __restrict__ b2,
                                                  const float* __restrict__ dw2,
                                                  const float* __restrict__ db2,
                                                  float* __restrict__ t2,
                                                  float* __restrict__ part) {
  __shared__ float wl[1024];
  __shared__ float c1[32][4];
  __shared__ float bias2[32];
  __shared__ float wred[8][32];
  for (int i = threadIdx.x; i < 1024; i += 256) wl[i] = w2[i] * dw2[i >> 5];
  if (threadIdx.x < 32) {
    int o = threadIdx.x;
    float dw = dw1[o], s1 = P1SC[o];
    c1[o][0] = w1[o * 3] * dw * s1;
    c1[o][1] = w1[o * 3 + 1] * dw * s1;
    c1[o][2] = w1[o * 3 + 2] * dw * s1;
    c1[o][3] = (b1[o] * dw + db1[o]) * s1 + P1SH[o];
    bias2[o] = b2[o] * dw2[o] + db2[o];
  }
  __syncthreads();
  const int p0 = blockIdx.x * 512 + threadIdx.x;
  const int b = p0 / HW, pp = p0 - b * HW;   // 512 | HW, no straddle
  const float* xb = xm + (size_t)b * 3 * HW + pp;
  float h[2][32];
#pragma unroll
  for (int q = 0; q < 2; ++q) {
    float x0 = xb[q * 256], x1 = xb[HW + q * 256], x2 = xb[2 * HW + q * 256];
#pragma unroll
    for (int o = 0; o < 32; ++o) {
      float u = fmaf(x0, c1[o][0], fmaf(x1, c1[o][1], fmaf(x2, c1[o][2], c1[o][3])));
      h[q][o] = lrelu01(u);
    }
  }
  float sv[32], sq[32];
  float* ob = t2 + (size_t)b * 32 * HW + pp;
  const float4* wl4 = reinterpret_cast<const float4*>(wl);
  for (int o = 0; o < 32; ++o) {
    float acc0 = bias2[o], acc1 = bias2[o];
#pragma unroll
    for (int c4 = 0; c4 < 8; ++c4) {
      float4 w4 = wl4[o * 8 + c4];
      int c = c4 * 4;
      acc0 = fmaf(h[0][c], w4.x, acc0);     acc1 = fmaf(h[1][c], w4.x, acc1);
      acc0 = fmaf(h[0][c + 1], w4.y, acc0); acc1 = fmaf(h[1][c + 1], w4.y, acc1);
      acc0 = fmaf(h[0][c + 2], w4.z, acc0); acc1 = fmaf(h[1][c + 2], w4.z, acc1);
      acc0 = fmaf(h[0][c + 3], w4.w, acc0); acc1 = fmaf(h[1][c + 3], w4.w, acc1);
    }
    ob[(size_t)o * HW] = acc0;
    ob[(size_t)o * HW + 256] = acc1;
    sv[o] = acc0 + acc1;
    sq[o] = acc0 * acc0 + acc1 * acc1;
  }
  int lane = threadIdx.x & 63, wd = threadIdx.x >> 6;
#pragma unroll
  for (int o = 0; o < 32; ++o) {
    float a = sv[o], q = sq[o];
    for (int off = 32; off; off >>= 1) {
      a += __shfl_down(a, off);
      q += __shfl_down(q, off);
    }
    if (lane == 0) { wred[wd][o] = a; wred[wd + 4][o] = q; }
  }
  __syncthreads();
  if (threadIdx.x < 32) {
    int o = threadIdx.x;
    part[((size_t)o * 2304 + blockIdx.x) * 2] = wred[0][o] + wred[1][o] + wred[2][o] + wred[3][o];
    part[((size_t)o * 2304 + blockIdx.x) * 2 + 1] = wred[4][o] + wred[5][o] + wred[6][o] + wred[7][o];
  }
}

// ---------------------------------------------------------------------------
// combine partials -> folded affine
// ---------------------------------------------------------------------------
__global__ __launch_bounds__(64) void stats_combine(const float* __restrict__ part, int nsplit,
                                                    const float* __restrict__ g,
                                                    const float* __restrict__ be,
                                                    float* __restrict__ sc,
                                                    float* __restrict__ sh) {
  const int c = blockIdx.x;
  double s = 0.0, q = 0.0;
  for (int i = threadIdx.x; i < nsplit; i += 64) {
    s += part[((size_t)c * nsplit + i) * 2];
    q += part[((size_t)c * nsplit + i) * 2 + 1];
  }
  for (int off = 32; off; off >>= 1) {
    s += __shfl_down(s, off);
    q += __shfl_down(q, off);
  }
  if (threadIdx.x == 0) {
    double mean = s / (double)NPC;
    double var = q / (double)NPC - mean * mean;
    float rstd = rsqrtf((float)var + 1e-5f);
    float scl = rstd * g[c];
    sc[c] = scl;
    sh[c] = be[c] - (float)mean * scl;
  }
}

// ---------------------------------------------------------------------------
// shared depthwise 3x3 stride-3 pad-1 conv; optional bn+lrelu on input
// ---------------------------------------------------------------------------
template <bool AFF>
__global__ __launch_bounds__(256) void dconv(const float* __restrict__ in,
                                             const float* __restrict__ sc,
                                             const float* __restrict__ sh,
                                             const float* __restrict__ w9,
                                             const float* __restrict__ db,
                                             int Sin, int Sout,
                                             float* __restrict__ out, int total) {
  int idx = blockIdx.x * 256 + threadIdx.x;
  if (idx >= total) return;
  int xx = idx % Sout;
  int t = idx / Sout;
  int yy = t % Sout;
  int pc = t / Sout;
  int c = pc & 31;
  const float* ip = in + (size_t)pc * Sin * Sin;
  float a = AFF ? sc[c] : 1.f;
  float h = AFF ? sh[c] : 0.f;
  float acc = 0.f;
#pragma unroll
  for (int ky = 0; ky < 3; ++ky) {
    int iy = 3 * yy - 1 + ky;
    if (iy < 0 || iy >= Sin) continue;
#pragma unroll
    for (int kx = 0; kx < 3; ++kx) {
      int ix = 3 * xx - 1 + kx;
      if (ix < 0 || ix >= Sin) continue;
      float v = ip[(size_t)iy * Sin + ix];
      if (AFF) { v = v * a + h; v = lrelu01(v); }
      acc = fmaf(v, w9[ky * 3 + kx], acc);
    }
  }
  out[idx] = acc + db[0];
}

// ---------------------------------------------------------------------------
// pyramid helpers. zt/dH stride 40 (16B aligned). Separable staging with
// vectorized y-interp; conv reads 2x float4 per row.
// ---------------------------------------------------------------------------
__device__ __forceinline__ void stage_geo2(int Sin, float scale, int tx, int ty,
                                           int* gx0, int* gx1, float* gfx, float* gxv,
                                           int* gy0, int* gy1, float* gfy, float* gyv) {
  if (threadIdx.x < 72) {
    int t = threadIdx.x >= 36 ? threadIdx.x - 36 : threadIdx.x;
    bool isY = threadIdx.x >= 36;
    int gp = (isY ? ty : tx) + t - 2;
    float valid = (gp >= 0 && gp < WID) ? 1.f : 0.f;
    int gpc = gp < 0 ? 0 : (gp >= WID ? WID - 1 : gp);
    float s = (gpc + 0.5f) * scale - 0.5f;
    float f0 = floorf(s);
    float fr = s - f0;
    int ii = (int)f0;
    int i1 = ii + 1 < Sin - 1 ? ii + 1 : Sin - 1;
    int i0 = ii > 0 ? ii : 0;
    if (isY) { gy0[t] = i0; gy1[t] = i1; gfy[t] = fr; gyv[t] = valid; }
    else     { gx0[t] = i0; gx1[t] = i1; gfx[t] = fr; gxv[t] = valid; }
  }
}

// dH: [<=16][40]; zt: [36][40]. Caller syncs before (geo ready) and after.
__device__ __forceinline__ void stage_sep(float* zt, float* dH, const float* dp, int Sin,
                                          const int* gx0, const int* gx1,
                                          const float* gfx, const float* gxv,
                                          const int* gy0, const int* gy1,
                                          const float* gfy, const float* gyv,
                                          int rowlo, int nrows) {
  for (int i = threadIdx.x; i < nrows * 36; i += 256) {
    int r = i / 36, zx = i - r * 36;
    const float* drow = dp + (size_t)(rowlo + r) * Sin;
    float v0 = drow[gx0[zx]], v1 = drow[gx1[zx]];
    dH[r * 40 + zx] = (v0 + gfx[zx] * (v1 - v0)) * gxv[zx];
  }
  __syncthreads();
  // vectorized y-interp: 36 rows x 9 float4 groups
  for (int i = threadIdx.x; i < 36 * 9; i += 256) {
    int zy = i / 9, k = i - zy * 9;
    int r0 = gy0[zy] - rowlo, r1 = gy1[zy] - rowlo;
    float fy = gfy[zy], vv = gyv[zy];
    float4 a = *reinterpret_cast<const float4*>(&dH[r0 * 40 + k * 4]);
    float4 b = *reinterpret_cast<const float4*>(&dH[r1 * 40 + k * 4]);
    float4 o;
    o.x = (a.x + fy * (b.x - a.x)) * vv;
    o.y = (a.y + fy * (b.y - a.y)) * vv;
    o.z = (a.z + fy * (b.z - a.z)) * vv;
    o.w = (a.w + fy * (b.w - a.w)) * vv;
    *reinterpret_cast<float4*>(&zt[zy * 40 + k * 4]) = o;
  }
}

__device__ __forceinline__ void conv_ab(const float* zt, int row, int g,
                                        const float* wa, const float* wb,
                                        float ba0, float bb0, float* A, float* Bv) {
  float aa0 = ba0, aa1 = ba0, aa2 = ba0, aa3 = ba0;
  float eb0 = bb0, eb1 = bb0, eb2 = bb0, eb3 = bb0;
#pragma unroll
  for (int dy = 0; dy < 5; ++dy) {
    const float* zr = &zt[(row + dy) * 40 + g * 4];
    float4 zlo = *reinterpret_cast<const float4*>(zr);
    float4 zhi = *reinterpret_cast<const float4*>(zr + 4);
    float z[8] = {zlo.x, zlo.y, zlo.z, zlo.w, zhi.x, zhi.y, zhi.z, zhi.w};
#pragma unroll
    for (int dx = 0; dx < 5; ++dx) {
      float wva = wa[dy * 5 + dx], wvb = wb[dy * 5 + dx];
      aa0 = fmaf(z[dx], wva, aa0);
      aa1 = fmaf(z[dx + 1], wva, aa1);
      aa2 = fmaf(z[dx + 2], wva, aa2);
      aa3 = fmaf(z[dx + 3], wva, aa3);
      eb0 = fmaf(z[dx], wvb, eb0);
      eb1 = fmaf(z[dx + 1], wvb, eb1);
      eb2 = fmaf(z[dx + 2], wvb, eb2);
      eb3 = fmaf(z[dx + 3], wvb, eb3);
    }
  }
  A[0] = aa0; A[1] = aa1; A[2] = aa2; A[3] = aa3;
  Bv[0] = eb0; Bv[1] = eb1; Bv[2] = eb2; Bv[3] = eb3;
}

// ---------------------------------------------------------------------------
// pyramid stats for ALL 5 levels (no output writes). grid (144, 256, 5).
// ---------------------------------------------------------------------------
__global__ __launch_bounds__(256) void upstats_all(const float* __restrict__ d1,
                                                   const float* __restrict__ d2,
                                                   const float* __restrict__ d3,
                                                   const float* __restrict__ d4,
                                                   const float* __restrict__ d5,
                                                   const float* __restrict__ wA5,
                                                   const float* __restrict__ wB5,
                                                   const float* __restrict__ bA,
                                                   const float* __restrict__ bB,
                                                   float* __restrict__ partA,
                                                   float* __restrict__ partB) {
  __shared__ __align__(16) float zt[36 * 40];
  __shared__ __align__(16) float dH[16 * 40];
  __shared__ int gx0[36], gx1[36], gy0[36], gy1[36];
  __shared__ float gfx[36], gfy[36], gxv[36], gyv[36];
  __shared__ float red[16];
  const int lvl = blockIdx.z;
  const float* dsel = lvl == 0 ? d1 : lvl == 1 ? d2 : lvl == 2 ? d3 : lvl == 3 ? d4 : d5;
  const int Sin = lvl == 0 ? 128 : lvl == 1 ? 43 : lvl == 2 ? 15 : lvl == 3 ? 5 : 2;
  const float scale = (float)Sin / 384.f;
  const int plane = blockIdx.y, tile = blockIdx.x;
  const int tx = (tile % 12) * 32, ty = (tile / 12) * 32;
  const float* dp = dsel + (size_t)plane * Sin * Sin;

  stage_geo2(Sin, scale, tx, ty, gx0, gx1, gfx, gxv, gy0, gy1, gfy, gyv);
  float wa[25], wb[25];
#pragma unroll
  for (int k = 0; k < 25; ++k) { wa[k] = wA5[k]; wb[k] = wB5[k]; }
  float ba0 = bA[0], bb0 = bB[0];
  __syncthreads();
  const int rowlo = gy0[0], nrows = gy1[35] - rowlo + 1;
  stage_sep(zt, dH, dp, Sin, gx0, gx1, gfx, gxv, gy0, gy1, gfy, gyv, rowlo, nrows);
  __syncthreads();

  float A[4], Bv[4];
  conv_ab(zt, threadIdx.x >> 3, threadIdx.x & 7, wa, wb, ba0, bb0, A, Bv);
  float sa = A[0] + A[1] + A[2] + A[3];
  float qa = A[0] * A[0] + A[1] * A[1] + A[2] * A[2] + A[3] * A[3];
  float sb = Bv[0] + Bv[1] + Bv[2] + Bv[3];
  float qb = Bv[0] * Bv[0] + Bv[1] * Bv[1] + Bv[2] * Bv[2] + Bv[3] * Bv[3];
  int lane = threadIdx.x & 63, wd = threadIdx.x >> 6;
  for (int off = 32; off; off >>= 1) {
    sa += __shfl_down(sa, off); qa += __shfl_down(qa, off);
    sb += __shfl_down(sb, off); qb += __shfl_down(qb, off);
  }
  if (lane == 0) {
    red[wd * 4] = sa; red[wd * 4 + 1] = qa;
    red[wd * 4 + 2] = sb; red[wd * 4 + 3] = qb;
  }
  __syncthreads();
  if (threadIdx.x == 0) {
    int b = plane >> 5, c = plane & 31;
    size_t pi = (size_t)lvl * 73728 + ((size_t)c * 1152 + (size_t)b * 144 + tile) * 2;
    partA[pi] = red[0] + red[4] + red[8] + red[12];
    partA[pi + 1] = red[1] + red[5] + red[9] + red[13];
    partB[pi] = red[2] + red[6] + red[10] + red[14];
    partB[pi + 1] = red[3] + red[7] + red[11] + red[15];
  }
}

// combine all 10 (level, conv) BN affines. grid (32, 5, 2).
__global__ __launch_bounds__(64) void combine_lvls(const float* __restrict__ partA,
                                                   const float* __restrict__ partB,
                                                   const float* __restrict__ ia_g,
                                                   const float* __restrict__ ia_be,
                                                   const float* __restrict__ ib_g,
                                                   const float* __restrict__ ib_be,
                                                   float* __restrict__ aff) {
  const int c = blockIdx.x, lvl = blockIdx.y, z = blockIdx.z;
  const float* part = (z ? partB : partA) + (size_t)lvl * 73728;
  const float* g = z ? ib_g : ia_g;
  const float* be = z ? ib_be : ia_be;
  double s = 0.0, q = 0.0;
  for (int i = threadIdx.x; i < 1152; i += 64) {
    s += part[((size_t)c * 1152 + i) * 2];
    q += part[((size_t)c * 1152 + i) * 2 + 1];
  }
  for (int off = 32; off; off >>= 1) {
    s += __shfl_down(s, off);
    q += __shfl_down(q, off);
  }
  if (threadIdx.x == 0) {
    double mean = s / (double)NPC;
    double var = q / (double)NPC - mean * mean;
    float rstd = rsqrtf((float)var + 1e-5f);
    float scl = rstd * g[c];
    aff[((z * 5 + lvl) * 2 + 0) * 32 + c] = scl;
    aff[((z * 5 + lvl) * 2 + 1) * 32 + c] = be[c] - (float)mean * scl;
  }
}

// ---------------------------------------------------------------------------
// apply ALL 5 levels: score = sum_lvl lrelu(bn(conv)) for both convs,
// single write + fused raw stats. grid (144, 256).
// ---------------------------------------------------------------------------
__global__ __launch_bounds__(256) void apply_all(const float* __restrict__ d1,
                                                 const float* __restrict__ d2,
                                                 const float* __restrict__ d3,
                                                 const float* __restrict__ d4,
                                                 const float* __restrict__ d5,
                                                 const float* __restrict__ wA5,
                                                 const float* __restrict__ wB5,
                                                 const float* __restrict__ bA,
                                                 const float* __restrict__ bB,
                                                 const float* __restrict__ aff,
                                                 float* __restrict__ outp,
                                                 float* __restrict__ partF) {
  __shared__ __align__(16) float zt[36 * 40];
  __shared__ __align__(16) float dH[16 * 40];
  __shared__ int gx0[36], gx1[36], gy0[36], gy1[36];
  __shared__ float gfx[36], gfy[36], gxv[36], gyv[36];
  __shared__ float red[16];
  const int plane = blockIdx.y, tile = blockIdx.x;
  const int tx = (tile % 12) * 32, ty = (tile / 12) * 32;
  const int b = plane >> 5, c = plane & 31;
  float wa[25], wb[25];
#pragma unroll
  for (int k = 0; k < 25; ++k) { wa[k] = wA5[k]; wb[k] = wB5[k]; }
  const float ba0 = bA[0], bb0 = bB[0];
  const int row = threadIdx.x >> 3, g = threadIdx.x & 7;

  float acA[4] = {0.f, 0.f, 0.f, 0.f}, acB[4] = {0.f, 0.f, 0.f, 0.f};
  for (int lvl = 0; lvl < 5; ++lvl) {
    const float* dsel = lvl == 0 ? d1 : lvl == 1 ? d2 : lvl == 2 ? d3 : lvl == 3 ? d4 : d5;
    const int Sin = lvl == 0 ? 128 : lvl == 1 ? 43 : lvl == 2 ? 15 : lvl == 3 ? 5 : 2;
    const float scale = (float)Sin / 384.f;
    const float* dp = dsel + (size_t)plane * Sin * Sin;
    __syncthreads();   // protect zt/dH/geo from previous iteration's readers
    stage_geo2(Sin, scale, tx, ty, gx0, gx1, gfx, gxv, gy0, gy1, gfy, gyv);
    __syncthreads();
    const int rowlo = gy0[0], nrows = gy1[35] - rowlo + 1;
    stage_sep(zt, dH, dp, Sin, gx0, gx1, gfx, gxv, gy0, gy1, gfy, gyv, rowlo, nrows);
    __syncthreads();
    float A[4], Bv[4];
    conv_ab(zt, row, g, wa, wb, ba0, bb0, A, Bv);
    float as = aff[(lvl * 2 + 0) * 32 + c], ah = aff[(lvl * 2 + 1) * 32 + c];
    float bs = aff[((5 + lvl) * 2 + 0) * 32 + c], bh = aff[((5 + lvl) * 2 + 1) * 32 + c];
#pragma unroll
    for (int j = 0; j < 4; ++j) {
      acA[j] += lrelu01(fmaf(A[j], as, ah));
      acB[j] += lrelu01(fmaf(Bv[j], bs, bh));
    }
  }
  float4 xa = {acA[0], acA[1], acA[2], acA[3]};
  float4 xb = {acB[0], acB[1], acB[2], acB[3]};
  size_t po = (size_t)(b * 64 + c) * HW + (size_t)(ty + row) * WID + tx + g * 4;
  *reinterpret_cast<float4*>(outp + po) = xa;
  *reinterpret_cast<float4*>(outp + po + (size_t)32 * HW) = xb;

  float sa = xa.x + xa.y + xa.z + xa.w;
  float qa = xa.x * xa.x + xa.y * xa.y + xa.z * xa.z + xa.w * xa.w;
  float sb = xb.x + xb.y + xb.z + xb.w;
  float qb = xb.x * xb.x + xb.y * xb.y + xb.z * xb.z + xb.w * xb.w;
  int lane = threadIdx.x & 63, wd = threadIdx.x >> 6;
  for (int off = 32; off; off >>= 1) {
    sa += __shfl_down(sa, off); qa += __shfl_down(qa, off);
    sb += __shfl_down(sb, off); qb += __shfl_down(qb, off);
  }
  if (lane == 0) {
    red[wd * 4] = sa; red[wd * 4 + 1] = qa;
    red[wd * 4 + 2] = sb; red[wd * 4 + 3] = qb;
  }
  __syncthreads();
  if (threadIdx.x == 0) {
    size_t piA = ((size_t)c * 1152 + (size_t)b * 144 + tile) * 2;
    size_t piB = ((size_t)(c + 32) * 1152 + (size_t)b * 144 + tile) * 2;
    partF[piA] = red[0] + red[4] + red[8] + red[12];
    partF[piA + 1] = red[1] + red[5] + red[9] + red[13];
    partF[piB] = red[2] + red[6] + red[10] + red[14];
    partF[piB + 1] = red[3] + red[7] + red[11] + red[15];
  }
}

// ---------------------------------------------------------------------------
// mlrelu(affine1(x)) stats, C=64, float4. grid = 64*64.
// ---------------------------------------------------------------------------
__global__ __launch_bounds__(256) void stats_mlrelu(const float4* __restrict__ X,
                                                    const float* __restrict__ sc1,
                                                    const float* __restrict__ sh1,
                                                    float* __restrict__ part) {
  int c = blockIdx.x >> 6, s = blockIdx.x & 63;
  float a1 = sc1[c], b1 = sh1[c];
  float sum = 0.f, sq = 0.f;
  int fi = s * 4608 + threadIdx.x;
#pragma unroll 2
  for (int it = 0; it < 18; ++it, fi += 256) {
    int b = fi / HW4, p4 = fi - b * HW4;
    float4 v = X[(size_t)(b * 64 + c) * HW4 + p4];
    float u;
    u = mlrelu(fmaf(v.x, a1, b1)); sum += u; sq += u * u;
    u = mlrelu(fmaf(v.y, a1, b1)); sum += u; sq += u * u;
    u = mlrelu(fmaf(v.z, a1, b1)); sum += u; sq += u * u;
    u = mlrelu(fmaf(v.w, a1, b1)); sum += u; sq += u * u;
  }
  int lane = threadIdx.x & 63, wd = threadIdx.x >> 6;
  for (int off = 32; off; off >>= 1) {
    sum += __shfl_down(sum, off);
    sq += __shfl_down(sq, off);
  }
  __shared__ float red[8];
  if (lane == 0) { red[wd * 2] = sum; red[wd * 2 + 1] = sq; }
  __syncthreads();
  if (threadIdx.x == 0) {
    part[((size_t)c * 64 + s) * 2] = red[0] + red[2] + red[4] + red[6];
    part[((size_t)c * 64 + s) * 2 + 1] = red[1] + red[3] + red[5] + red[7];
  }
}

// ---------------------------------------------------------------------------
// fused ft pass, bank-conflict-free: sl stride 81, Hl stride 64 float4.
// grid (36, 512).
// ---------------------------------------------------------------------------
__global__ __launch_bounds__(256) void ft_fused(const float* __restrict__ src,
                                                const float* __restrict__ F1SC,
                                                const float* __restrict__ F1SH,
                                                const float* __restrict__ F2SC,
                                                const float* __restrict__ F2SH,
                                                float* __restrict__ dst, float fscale,
                                                float* __restrict__ part) {
  __shared__ float sl[74 * 81];
  __shared__ __align__(16) float Hl[74 * 64];
  __shared__ float red[8];
  const int tile = blockIdx.x;
  const int plane = blockIdx.y;
  const int b = plane >> 6, c = plane & 63;
  const int tx = (tile % 6) * 64, ty = (tile / 6) * 64;
  const float a1 = F1SC[c], b1 = F1SH[c], a2 = F2SC[c], b2 = F2SH[c];
  const float* sp = src + (size_t)plane * HW;

  for (int i = threadIdx.x; i < 74 * 20; i += 256) {
    int r = i / 20, k = i - r * 20;
    int gy = ty + r - 5, gx = tx + k * 4 - 8;
    float4 sv = {0.f, 0.f, 0.f, 0.f};
    if (gy >= 0 && gy < WID && gx >= 0 && gx < WID) {
      float4 v = *reinterpret_cast<const float4*>(sp + (size_t)gy * WID + gx);
      sv.x = fmaf(mlrelu(fmaf(v.x, a1, b1)), a2, b2);
      sv.y = fmaf(mlrelu(fmaf(v.y, a1, b1)), a2, b2);
      sv.z = fmaf(mlrelu(fmaf(v.z, a1, b1)), a2, b2);
      sv.w = fmaf(mlrelu(fmaf(v.w, a1, b1)), a2, b2);
    }
    int base = r * 81 + k * 4;
    sl[base] = sv.x; sl[base + 1] = sv.y; sl[base + 2] = sv.z; sl[base + 3] = sv.w;
  }
  __syncthreads();

  for (int i = threadIdx.x; i < 74 * 16; i += 256) {
    int r = i >> 4, g = i & 15;
    const float* s0 = &sl[r * 81 + g * 4 + 3];
    float v[14];
#pragma unroll
    for (int j = 0; j < 14; ++j) v[j] = s0[j];
    float h0 = v[0] + v[1] + v[2] + v[3] + v[4] + v[5] + v[6] + v[7] + v[8] + v[9] + v[10];
    float h1 = h0 - v[0] + v[11];
    float h2 = h1 - v[1] + v[12];
    float h3 = h2 - v[2] + v[13];
    float4 hh = {h0, h1, h2, h3};
    *reinterpret_cast<float4*>(&Hl[r * 64 + g * 4]) = hh;
  }
  __syncthreads();

  const int g = threadIdx.x & 15, ly = threadIdx.x >> 4;
  const int y0 = ly * 4;
  const float4* H4 = reinterpret_cast<const float4*>(Hl);
  float4 acc = H4[y0 * 16 + g];
#pragma unroll
  for (int dy = 1; dy < 11; ++dy) {
    float4 t = H4[(y0 + dy) * 16 + g];
    acc.x += t.x; acc.y += t.y; acc.z += t.z; acc.w += t.w;
  }
  float sum = 0.f, sq = 0.f;
  float* dpo = dst + (size_t)plane * HW;
#pragma unroll
  for (int ry = 0; ry < 4; ++ry) {
    int y = y0 + ry;
    if (ry) {
      float4 ta = H4[(y + 10) * 16 + g];
      float4 tb = H4[(y - 1) * 16 + g];
      acc.x += ta.x - tb.x; acc.y += ta.y - tb.y;
      acc.z += ta.z - tb.z; acc.w += ta.w - tb.w;
    }
    const float* cp = &sl[(y + 5) * 81 + g * 4 + 8];
    float4 o;
    o.x = (2.f * cp[0] - acc.x * (1.f / 121.f)) * fscale;
    o.y = (2.f * cp[1] - acc.y * (1.f / 121.f)) * fscale;
    o.z = (2.f * cp[2] - acc.z * (1.f / 121.f)) * fscale;
    o.w = (2.f * cp[3] - acc.w * (1.f / 121.f)) * fscale;
    *reinterpret_cast<float4*>(dpo + (size_t)(ty + y) * WID + tx + g * 4) = o;
    sum += o.x + o.y + o.z + o.w;
    sq += o.x * o.x + o.y * o.y + o.z * o.z + o.w * o.w;
  }
  if (part) {
    int lane = threadIdx.x & 63, wd = threadIdx.x >> 6;
    for (int off = 32; off; off >>= 1) {
      sum += __shfl_down(sum, off);
      sq += __shfl_down(sq, off);
    }
    if (lane == 0) { red[wd * 2] = sum; red[wd * 2 + 1] = sq; }
    __syncthreads();
    if (threadIdx.x == 0) {
      size_t pi = ((size_t)c * 288 + (size_t)b * 36 + tile) * 2;
      part[pi] = red[0] + red[2] + red[4] + red[6];
      part[pi + 1] = red[1] + red[3] + red[5] + red[7];
    }
  }
}

// ---------------------------------------------------------------------------
extern "C" void kernel_launch(void* const* d_in, const int* in_sizes, int n_in,
                              void* d_out, int out_size, void* d_ws, size_t ws_size,
                              hipStream_t stream) {
  const float* x     = (const float*)d_in[0];
  const float* p_w1  = (const float*)d_in[1];
  const float* p_b1  = (const float*)d_in[2];
  const float* p_dw1 = (const float*)d_in[3];
  const float* p_db1 = (const float*)d_in[4];
  const float* p_g1  = (const float*)d_in[5];
  const float* p_be1 = (const float*)d_in[6];
  const float* p_w2  = (const float*)d_in[7];
  const float* p_b2  = (const float*)d_in[8];
  const float* p_dw2 = (const float*)d_in[9];
  const float* p_db2 = (const float*)d_in[10];
  const float* p_g2  = (const float*)d_in[11];
  const float* p_be2 = (const float*)d_in[12];
  const float* d_w   = (const float*)d_in[13];
  const float* d_b   = (const float*)d_in[14];
  const float* ia_w  = (const float*)d_in[15];
  const float* ia_b  = (const float*)d_in[16];
  const float* ia_g  = (const float*)d_in[17];
  const float* ia_be = (const float*)d_in[18];
  const float* ib_w  = (const float*)d_in[19];
  const float* ib_b  = (const float*)d_in[20];
  const float* ib_g  = (const float*)d_in[21];
  const float* ib_be = (const float*)d_in[22];
  const float* f_g1  = (const float*)d_in[23];
  const float* f_be1 = (const float*)d_in[24];
  const float* f_g2  = (const float*)d_in[25];
  const float* f_be2 = (const float*)d_in[26];
  float* out = (float*)d_out;
  float* ws = (float*)d_ws;

  const size_t SLOT = 37748736ull;  // 8*32*384*384 floats; score = 2*SLOT
  float* B0 = ws;
  float* B1 = ws + 2 * SLOT;
  float* t2 = B0;
  float* partA = B0 + SLOT;                // 368,640  [5][32][1152][2]
  float* partB = partA + 368640;           // 368,640
  float* partP = partB + 368640;           // 147,456  [32][2304][2]
  float* part9 = partP + 147456;           // 2,304    [256][9]
  float* aff   = part9 + 2304;             // 640      [2][5][2][32]
  float* xm  = B1;                         // 3,538,944
  float* dd1 = xm + 3538944;               // 4,194,304
  float* dd2 = dd1 + 4194304;              // 473,344
  float* dd3 = dd2 + 473344;               // 57,600
  float* dd4 = dd3 + 57600;                // 6,400
  float* dd5 = dd4 + 6400;                 // 1,024
  float* partF = ws + 4 * SLOT;            // 147,456  [64][1152][2]
  float* partS = partF + 147456;           // 8,192    [64][64][2]
  float* st    = partS + 8192;             // 512

  float* P1SC = st,       *P1SH = st + 32;
  float* P2SC = st + 64,  *P2SH = st + 96;
  float* F1SC = st + 128, *F1SH = st + 192;
  float* F2SC = st + 256, *F2SH = st + 320;

  // mode + prepare (t1 never materialized; BN1 affine analytic from xm moments)
  mode_kernel<<<dim3(6, 24, 24), 256, 0, stream>>>(x, xm);
  xm_mom<<<256, 256, 0, stream>>>((const float4*)xm, part9);
  prep1_affine<<<1, 64, 0, stream>>>(part9, p_w1, p_b1, p_dw1, p_db1, p_g1, p_be1, P1SC, P1SH);
  prep_fused<<<2304, 256, 0, stream>>>(xm, p_w1, p_b1, p_dw1, p_db1, P1SC, P1SH,
                                       p_w2, p_b2, p_dw2, p_db2, t2, partP);
  stats_combine<<<32, 64, 0, stream>>>(partP, 2304, p_g2, p_be2, P2SC, P2SH);

  // pyramid d-chain
  dconv<true><<<16384, 256, 0, stream>>>(t2, P2SC, P2SH, d_w, d_b, 384, 128, dd1,
                                         8 * 32 * 128 * 128);
  dconv<false><<<(8 * 32 * 43 * 43 + 255) / 256, 256, 0, stream>>>(
      dd1, nullptr, nullptr, d_w, d_b, 128, 43, dd2, 8 * 32 * 43 * 43);
  dconv<false><<<(8 * 32 * 15 * 15 + 255) / 256, 256, 0, stream>>>(
      dd2, nullptr, nullptr, d_w, d_b, 43, 15, dd3, 8 * 32 * 15 * 15);
  dconv<false><<<(8 * 32 * 5 * 5 + 255) / 256, 256, 0, stream>>>(
      dd3, nullptr, nullptr, d_w, d_b, 15, 5, dd4, 8 * 32 * 5 * 5);
  dconv<false><<<(8 * 32 * 2 * 2 + 255) / 256, 256, 0, stream>>>(
      dd4, nullptr, nullptr, d_w, d_b, 5, 2, dd5, 8 * 32 * 2 * 2);

  // all-level stats, then single-write apply with fused score stats
  upstats_all<<<dim3(144, 256, 5), 256, 0, stream>>>(dd1, dd2, dd3, dd4, dd5,
                                                     ia_w, ib_w, ia_b, ib_b, partA, partB);
  combine_lvls<<<dim3(32, 5, 2), 64, 0, stream>>>(partA, partB, ia_g, ia_be, ib_g, ib_be, aff);
  apply_all<<<dim3(144, 256), 256, 0, stream>>>(dd1, dd2, dd3, dd4, dd5,
                                                ia_w, ib_w, ia_b, ib_b, aff, out, partF);

  // ft chain x3; rotation out -> B0 -> B1 -> out (no aliasing, halo-safe)
  const float* cur = out;
  float* dsts[3] = {B0, B1, out};
  for (int k = 0; k < 3; ++k) {
    stats_combine<<<64, 64, 0, stream>>>(partF, (k == 0) ? 1152 : 288, f_g1, f_be1, F1SC, F1SH);
    stats_mlrelu<<<64 * 64, 256, 0, stream>>>((const float4*)cur, F1SC, F1SH, partS);
    stats_combine<<<64, 64, 0, stream>>>(partS, 64, f_g2, f_be2, F2SC, F2SH);
    ft_fused<<<dim3(36, 512), 256, 0, stream>>>(cur, F1SC, F1SH, F2SC, F2SH, dsts[k],
                                                (k == 2) ? 0.2f : 1.0f,
                                                (k < 2) ? partF : nullptr);
    cur = dsts[k];
  }
}